// Round 1
// baseline (2407.297 us; speedup 1.0000x reference)
//
#include <hip/hip_runtime.h>
#include <hip/hip_bf16.h>
#include <math.h>

#define NN 50000
#define EE 800000
#define EPE 850000   // EE + NN self loops
#define HCC 128
#define GGR 256
#define NHIDD 512
#define NOUTD 768

__device__ __forceinline__ void atomicMaxF(float* addr, float v) {
    if (v >= 0.f) atomicMax(reinterpret_cast<int*>(addr), __float_as_int(v));
    else atomicMin(reinterpret_cast<unsigned int*>(addr), __float_as_uint(v));
}

__device__ __forceinline__ float lrelu(float x) { return x > 0.f ? x : 0.2f * x; }

// C[64 rows][64 cols] tile of  [N,128] @ [128,256]  where cols<128 -> W (h out),
// cols>=128 -> SKW (skip out, + skb + b epilogue).
__global__ __launch_bounds__(256) void gemm_node(
    const float* __restrict__ X, const float* __restrict__ W, const float* __restrict__ SKW,
    const float* __restrict__ skb, const float* __restrict__ bb,
    float* __restrict__ Hout, float* __restrict__ Agg)
{
    __shared__ float Xs[128][68];   // [k][m]
    __shared__ float Ws[128][68];   // [k][c]
    const int row0 = blockIdx.x * 64;
    const int bc = blockIdx.y;                 // 0..3
    const int tid = threadIdx.x;
    const float* M = (bc < 2) ? W : SKW;
    const int colOff = (bc & 1) * 64;

    // stage X tile (transposed)
    {
        int m = tid >> 2;
        int kq = (tid & 3) * 4;
        int n = row0 + m;
        #pragma unroll
        for (int it = 0; it < 8; ++it) {
            int k = kq + it * 16;
            float4 v = make_float4(0.f, 0.f, 0.f, 0.f);
            if (n < NN) v = *reinterpret_cast<const float4*>(X + (size_t)n * 128 + k);
            Xs[k + 0][m] = v.x; Xs[k + 1][m] = v.y; Xs[k + 2][m] = v.z; Xs[k + 3][m] = v.w;
        }
    }
    // stage W tile
    {
        int kr = tid >> 4;
        int c4 = (tid & 15) * 4;
        #pragma unroll
        for (int it = 0; it < 8; ++it) {
            int k = it * 16 + kr;
            float4 v = *reinterpret_cast<const float4*>(M + (size_t)k * 128 + colOff + c4);
            *reinterpret_cast<float4*>(&Ws[k][c4]) = v;
        }
    }
    __syncthreads();

    const int tx = tid & 15, ty = tid >> 4;
    float acc[4][4] = {};
    #pragma unroll 4
    for (int k = 0; k < 128; ++k) {
        float4 a = *reinterpret_cast<const float4*>(&Xs[k][ty * 4]);
        float4 b = *reinterpret_cast<const float4*>(&Ws[k][tx * 4]);
        float av[4] = {a.x, a.y, a.z, a.w};
        float bv[4] = {b.x, b.y, b.z, b.w};
        #pragma unroll
        for (int i = 0; i < 4; ++i) {
            #pragma unroll
            for (int j = 0; j < 4; ++j) acc[i][j] += av[i] * bv[j];
        }
    }

    #pragma unroll
    for (int i = 0; i < 4; ++i) {
        int n = row0 + ty * 4 + i;
        if (n >= NN) continue;
        int c = colOff + tx * 4;
        if (bc < 2) {
            float4 v = make_float4(acc[i][0], acc[i][1], acc[i][2], acc[i][3]);
            *reinterpret_cast<float4*>(Hout + (size_t)n * 128 + c) = v;
        } else {
            float4 v;
            v.x = acc[i][0] + skb[c + 0] + bb[c + 0];
            v.y = acc[i][1] + skb[c + 1] + bb[c + 1];
            v.z = acc[i][2] + skb[c + 2] + bb[c + 2];
            v.w = acc[i][3] + skb[c + 3] + bb[c + 3];
            *reinterpret_cast<float4*>(Agg + (size_t)n * 128 + c) = v;
        }
    }
}

// per-node attention coefficients e_src/e_dst [N,4]
__global__ __launch_bounds__(256) void node_attn(
    const float* __restrict__ Hf, const float* __restrict__ as_, const float* __restrict__ ad_,
    float* __restrict__ esrc, float* __restrict__ edst)
{
    int tid = threadIdx.x;
    int node = blockIdx.x * 2 + (tid >> 7);
    int t = tid & 127;
    if (node >= NN) return;
    float hv = Hf[(size_t)node * 128 + t];
    float p1 = hv * as_[t];
    float p2 = hv * ad_[t];
    #pragma unroll
    for (int o = 16; o > 0; o >>= 1) {
        p1 += __shfl_down(p1, o, 32);
        p2 += __shfl_down(p2, o, 32);
    }
    if ((t & 31) == 0) {
        esrc[node * 4 + (t >> 5)] = p1;
        edst[node * 4 + (t >> 5)] = p2;
    }
}

__global__ void init_mz(float* __restrict__ m, float* __restrict__ z) {
    int i = blockIdx.x * 256 + threadIdx.x;
    if (i < NN * 4) { m[i] = -INFINITY; z[i] = 0.f; }
}

__global__ void edge_max(const int* __restrict__ ei, const float* __restrict__ esrc,
                         const float* __restrict__ edst, float* __restrict__ m,
                         float* __restrict__ ebuf)
{
    int e = blockIdx.x * 256 + threadIdx.x;
    if (e >= EPE) return;
    int s, d;
    if (e < EE) { s = ei[e]; d = ei[EE + e]; } else { s = d = e - EE; }
    float4 a = *reinterpret_cast<const float4*>(esrc + (size_t)s * 4);
    float4 b = *reinterpret_cast<const float4*>(edst + (size_t)d * 4);
    float4 ev;
    ev.x = lrelu(a.x + b.x); ev.y = lrelu(a.y + b.y);
    ev.z = lrelu(a.z + b.z); ev.w = lrelu(a.w + b.w);
    *reinterpret_cast<float4*>(ebuf + (size_t)e * 4) = ev;
    atomicMaxF(&m[d * 4 + 0], ev.x);
    atomicMaxF(&m[d * 4 + 1], ev.y);
    atomicMaxF(&m[d * 4 + 2], ev.z);
    atomicMaxF(&m[d * 4 + 3], ev.w);
}

__global__ void edge_exp(const int* __restrict__ ei, const float* __restrict__ m,
                         float* __restrict__ ebuf, float* __restrict__ z)
{
    int e = blockIdx.x * 256 + threadIdx.x;
    if (e >= EPE) return;
    int d = (e < EE) ? ei[EE + e] : e - EE;
    float4 ev = *reinterpret_cast<const float4*>(ebuf + (size_t)e * 4);
    float4 mv = *reinterpret_cast<const float4*>(m + (size_t)d * 4);
    float4 ex;
    ex.x = __expf(ev.x - mv.x); ex.y = __expf(ev.y - mv.y);
    ex.z = __expf(ev.z - mv.z); ex.w = __expf(ev.w - mv.w);
    *reinterpret_cast<float4*>(ebuf + (size_t)e * 4) = ex;
    atomicAdd(&z[d * 4 + 0], ex.x);
    atomicAdd(&z[d * 4 + 1], ex.y);
    atomicAdd(&z[d * 4 + 2], ex.z);
    atomicAdd(&z[d * 4 + 3], ex.w);
}

// 128 threads per edge: channel gather of h[src], atomic scatter into agg[dst]
__global__ __launch_bounds__(256) void edge_aggr(
    const int* __restrict__ ei, const float* __restrict__ ebuf, const float* __restrict__ z,
    const float* __restrict__ Hf, float* __restrict__ agg)
{
    int tid = threadIdx.x;
    int e = blockIdx.x * 2 + (tid >> 7);
    if (e >= EPE) return;
    int c = tid & 127;
    int s, d;
    if (e < EE) { s = ei[e]; d = ei[EE + e]; } else { s = d = e - EE; }
    int hd = c >> 5;
    float alpha = ebuf[(size_t)e * 4 + hd] / z[d * 4 + hd];
    atomicAdd(&agg[(size_t)d * 128 + c], alpha * Hf[(size_t)s * 128 + c]);
}

__global__ void relu_copy(const float* __restrict__ a, float* __restrict__ o) {
    int i = blockIdx.x * 256 + threadIdx.x;
    if (i < NN * 32) {
        float4 v = reinterpret_cast<const float4*>(a)[i];
        v.x = fmaxf(v.x, 0.f); v.y = fmaxf(v.y, 0.f);
        v.z = fmaxf(v.z, 0.f); v.w = fmaxf(v.w, 0.f);
        reinterpret_cast<float4*>(o)[i] = v;
    }
}

__global__ void pool_init(float* __restrict__ pooled) {
    int i = blockIdx.x * 256 + threadIdx.x;
    if (i < GGR * HCC) pooled[i] = -INFINITY;
}

__global__ void pool_max(const float* __restrict__ xf, const int* __restrict__ batch,
                         float* __restrict__ pooled)
{
    int i = blockIdx.x * 256 + threadIdx.x;
    if (i >= NN * HCC) return;
    int n = i >> 7, c = i & 127;
    atomicMaxF(&pooled[batch[n] * 128 + c], xf[i]);
}

__global__ __launch_bounds__(512) void mlp1(const float* __restrict__ pooled,
                                            const float* __restrict__ w,
                                            const float* __restrict__ bias,
                                            float* __restrict__ hid)
{
    __shared__ float xs[128];
    int g = blockIdx.x, t = threadIdx.x;
    if (t < 128) {
        float v = pooled[g * 128 + t];
        if (!isfinite(v)) v = 0.f;
        xs[t] = v;
    }
    __syncthreads();
    float acc = 0.f;
    #pragma unroll 8
    for (int k = 0; k < 128; ++k) acc += xs[k] * w[(size_t)k * NHIDD + t];
    hid[(size_t)g * NHIDD + t] = fmaxf(acc + bias[t], 0.f);
}

__global__ __launch_bounds__(768) void mlp2(const float* __restrict__ hid,
                                            const float* __restrict__ w,
                                            const float* __restrict__ bias,
                                            float* __restrict__ out)
{
    __shared__ float xs[NHIDD];
    int g = blockIdx.x, t = threadIdx.x;
    if (t < NHIDD) xs[t] = hid[(size_t)g * NHIDD + t];
    __syncthreads();
    float acc = 0.f;
    #pragma unroll 8
    for (int k = 0; k < NHIDD; ++k) acc += xs[k] * w[(size_t)k * NOUTD + t];
    out[(size_t)g * NOUTD + t] = acc + bias[t];
}

extern "C" void kernel_launch(void* const* d_in, const int* in_sizes, int n_in,
                              void* d_out, int out_size, void* d_ws, size_t ws_size,
                              hipStream_t stream)
{
    const float* x = (const float*)d_in[0];
    const int* ei = (const int*)d_in[1];
    const int* batch = (const int*)d_in[2];
    const float* W[3]   = {(const float*)d_in[3],  (const float*)d_in[9],  (const float*)d_in[15]};
    const float* AS[3]  = {(const float*)d_in[4],  (const float*)d_in[10], (const float*)d_in[16]};
    const float* AD[3]  = {(const float*)d_in[5],  (const float*)d_in[11], (const float*)d_in[17]};
    const float* B[3]   = {(const float*)d_in[6],  (const float*)d_in[12], (const float*)d_in[18]};
    const float* SKW[3] = {(const float*)d_in[7],  (const float*)d_in[13], (const float*)d_in[19]};
    const float* SKB[3] = {(const float*)d_in[8],  (const float*)d_in[14], (const float*)d_in[20]};
    const float* m1w = (const float*)d_in[21];
    const float* m1b = (const float*)d_in[22];
    const float* m2w = (const float*)d_in[23];
    const float* m2b = (const float*)d_in[24];
    float* out = (float*)d_out;

    float* p = (float*)d_ws;
    float* bufA = p; p += (size_t)NN * HCC;
    float* bufB = p; p += (size_t)NN * HCC;
    float* hbuf = p; p += (size_t)NN * HCC;
    float* agg  = p; p += (size_t)NN * HCC;
    float* esrc = p; p += NN * 4;
    float* edst = p; p += NN * 4;
    float* mbuf = p; p += NN * 4;
    float* zbuf = p; p += NN * 4;
    float* ebuf = p; p += (size_t)EPE * 4;
    float* pooled = p; p += GGR * HCC;
    float* hidden = p; p += GGR * NHIDD;

    const float* cur = x;
    float* outs[3] = {bufA, bufB, bufA};
    for (int l = 0; l < 3; ++l) {
        dim3 gg((NN + 63) / 64, 4);
        gemm_node<<<gg, 256, 0, stream>>>(cur, W[l], SKW[l], SKB[l], B[l], hbuf, agg);
        node_attn<<<NN / 2, 256, 0, stream>>>(hbuf, AS[l], AD[l], esrc, edst);
        init_mz<<<(NN * 4 + 255) / 256, 256, 0, stream>>>(mbuf, zbuf);
        edge_max<<<(EPE + 255) / 256, 256, 0, stream>>>(ei, esrc, edst, mbuf, ebuf);
        edge_exp<<<(EPE + 255) / 256, 256, 0, stream>>>(ei, mbuf, ebuf, zbuf);
        edge_aggr<<<EPE / 2, 256, 0, stream>>>(ei, ebuf, zbuf, hbuf, agg);
        relu_copy<<<(NN * 32 + 255) / 256, 256, 0, stream>>>(agg, outs[l]);
        cur = outs[l];
    }
    pool_init<<<(GGR * HCC) / 256, 256, 0, stream>>>(pooled);
    pool_max<<<(NN * HCC + 255) / 256, 256, 0, stream>>>(cur, batch, pooled);
    mlp1<<<GGR, NHIDD, 0, stream>>>(pooled, m1w, m1b, hidden);
    mlp2<<<GGR, NOUTD, 0, stream>>>(hidden, m2w, m2b, out);
}

// Round 2
// 809.603 us; speedup vs baseline: 2.9734x; 2.9734x over previous
//
#include <hip/hip_runtime.h>
#include <hip/hip_bf16.h>
#include <math.h>

#define NN 50000
#define EE 800000
#define EPE 850000   // EE + NN self loops
#define HCC 128
#define GGR 256
#define NHIDD 512
#define NOUTD 768
#define CHUNK 256

__device__ __forceinline__ void atomicMaxF(float* addr, float v) {
    if (v >= 0.f) atomicMax(reinterpret_cast<int*>(addr), __float_as_int(v));
    else atomicMin(reinterpret_cast<unsigned int*>(addr), __float_as_uint(v));
}

__device__ __forceinline__ float lrelu(float x) { return x > 0.f ? x : 0.2f * x; }

// ---------------- CSR build (once per call) ----------------
__global__ void hist_zero(int* __restrict__ counts) {
    int i = blockIdx.x * 256 + threadIdx.x;
    if (i < NN) counts[i] = 0;
}

__global__ void hist(const int* __restrict__ ei, int* __restrict__ counts) {
    int e = blockIdx.x * 256 + threadIdx.x;
    if (e >= EPE) return;
    int d = (e < EE) ? ei[EE + e] : e - EE;
    atomicAdd(&counts[d], 1);
}

__global__ __launch_bounds__(1024) void scan_rows(const int* __restrict__ counts,
                                                  int* __restrict__ row_start,
                                                  int* __restrict__ cursor) {
    __shared__ int s[1024];
    __shared__ int carry;
    int t = threadIdx.x;
    if (t == 0) carry = 0;
    __syncthreads();
    for (int base = 0; base < NN; base += 1024) {
        int i = base + t;
        int v = (i < NN) ? counts[i] : 0;
        s[t] = v;
        __syncthreads();
        #pragma unroll
        for (int off = 1; off < 1024; off <<= 1) {
            int add = (t >= off) ? s[t - off] : 0;
            __syncthreads();
            s[t] += add;
            __syncthreads();
        }
        int excl = carry + s[t] - v;
        if (i < NN) { row_start[i] = excl; cursor[i] = excl; }
        __syncthreads();
        if (t == 1023) carry += s[1023];
        __syncthreads();
    }
    if (t == 0) row_start[NN] = carry;
}

__global__ void scatter_csr(const int* __restrict__ ei, int* __restrict__ cursor,
                            int* __restrict__ csr_src) {
    int e = blockIdx.x * 256 + threadIdx.x;
    if (e >= EPE) return;
    int s, d;
    if (e < EE) { s = ei[e]; d = ei[EE + e]; } else { s = d = e - EE; }
    int pos = atomicAdd(&cursor[d], 1);
    csr_src[pos] = s;
}

// ---------------- node GEMM (h and skip) ----------------
__global__ __launch_bounds__(256) void gemm_node(
    const float* __restrict__ X, const float* __restrict__ W, const float* __restrict__ SKW,
    const float* __restrict__ skb, const float* __restrict__ bb,
    float* __restrict__ Hout, float* __restrict__ Agg)
{
    __shared__ float Xs[128][68];   // [k][m]
    __shared__ float Ws[128][68];   // [k][c]
    const int row0 = blockIdx.x * 64;
    const int bc = blockIdx.y;                 // 0..3
    const int tid = threadIdx.x;
    const float* M = (bc < 2) ? W : SKW;
    const int colOff = (bc & 1) * 64;

    {
        int m = tid >> 2;
        int kq = (tid & 3) * 4;
        int n = row0 + m;
        #pragma unroll
        for (int it = 0; it < 8; ++it) {
            int k = kq + it * 16;
            float4 v = make_float4(0.f, 0.f, 0.f, 0.f);
            if (n < NN) v = *reinterpret_cast<const float4*>(X + (size_t)n * 128 + k);
            Xs[k + 0][m] = v.x; Xs[k + 1][m] = v.y; Xs[k + 2][m] = v.z; Xs[k + 3][m] = v.w;
        }
    }
    {
        int kr = tid >> 4;
        int c4 = (tid & 15) * 4;
        #pragma unroll
        for (int it = 0; it < 8; ++it) {
            int k = it * 16 + kr;
            float4 v = *reinterpret_cast<const float4*>(M + (size_t)k * 128 + colOff + c4);
            *reinterpret_cast<float4*>(&Ws[k][c4]) = v;
        }
    }
    __syncthreads();

    const int tx = tid & 15, ty = tid >> 4;
    float acc[4][4] = {};
    #pragma unroll 4
    for (int k = 0; k < 128; ++k) {
        float4 a = *reinterpret_cast<const float4*>(&Xs[k][ty * 4]);
        float4 b = *reinterpret_cast<const float4*>(&Ws[k][tx * 4]);
        float av[4] = {a.x, a.y, a.z, a.w};
        float bv[4] = {b.x, b.y, b.z, b.w};
        #pragma unroll
        for (int i = 0; i < 4; ++i) {
            #pragma unroll
            for (int j = 0; j < 4; ++j) acc[i][j] += av[i] * bv[j];
        }
    }

    #pragma unroll
    for (int i = 0; i < 4; ++i) {
        int n = row0 + ty * 4 + i;
        if (n >= NN) continue;
        int c = colOff + tx * 4;
        if (bc < 2) {
            float4 v = make_float4(acc[i][0], acc[i][1], acc[i][2], acc[i][3]);
            *reinterpret_cast<float4*>(Hout + (size_t)n * 128 + c) = v;
        } else {
            float4 v;
            v.x = acc[i][0] + skb[c + 0] + bb[c + 0];
            v.y = acc[i][1] + skb[c + 1] + bb[c + 1];
            v.z = acc[i][2] + skb[c + 2] + bb[c + 2];
            v.w = acc[i][3] + skb[c + 3] + bb[c + 3];
            *reinterpret_cast<float4*>(Agg + (size_t)n * 128 + c) = v;
        }
    }
}

// per-node attention coefficients e_src/e_dst [N,4]
__global__ __launch_bounds__(256) void node_attn(
    const float* __restrict__ Hf, const float* __restrict__ as_, const float* __restrict__ ad_,
    float* __restrict__ esrc, float* __restrict__ edst)
{
    int tid = threadIdx.x;
    int node = blockIdx.x * 2 + (tid >> 7);
    int t = tid & 127;
    if (node >= NN) return;
    float hv = Hf[(size_t)node * 128 + t];
    float p1 = hv * as_[t];
    float p2 = hv * ad_[t];
    #pragma unroll
    for (int o = 16; o > 0; o >>= 1) {
        p1 += __shfl_down(p1, o, 32);
        p2 += __shfl_down(p2, o, 32);
    }
    if ((t & 31) == 0) {
        esrc[node * 4 + (t >> 5)] = p1;
        edst[node * 4 + (t >> 5)] = p2;
    }
}

// ---------------- fused per-dst softmax + aggregate + skip + relu ----------------
__global__ __launch_bounds__(128) void gat_aggr(
    const int* __restrict__ row_start, const int* __restrict__ csr_src,
    const float* __restrict__ esrc, const float* __restrict__ edst,
    const float* __restrict__ Hf, const float* __restrict__ skipagg,
    float* __restrict__ outbuf)
{
    __shared__ int   lsrc[CHUNK];
    __shared__ float lw[CHUNK * 4];
    __shared__ float shm[4], shz[4], shscale[4];
    const int d = blockIdx.x;
    const int t = threadIdx.x;
    const int hd = t >> 5;
    const int r0 = row_start[d], r1 = row_start[d + 1];
    const float4 edv = *reinterpret_cast<const float4*>(edst + (size_t)d * 4);
    float acc = 0.f;
    if (t < 4) { shm[t] = -INFINITY; shz[t] = 0.f; }
    __syncthreads();

    for (int base = r0; base < r1; base += CHUNK) {
        const int nc = min(CHUNK, r1 - base);
        for (int i = t; i < nc; i += 128) {
            int s = csr_src[base + i];
            lsrc[i] = s;
            float4 ev = *reinterpret_cast<const float4*>(esrc + (size_t)s * 4);
            lw[i * 4 + 0] = lrelu(ev.x + edv.x);
            lw[i * 4 + 1] = lrelu(ev.y + edv.y);
            lw[i * 4 + 2] = lrelu(ev.z + edv.z);
            lw[i * 4 + 3] = lrelu(ev.w + edv.w);
        }
        __syncthreads();
        if (t < 4) {
            float m_old = shm[t];
            float mx = m_old;
            for (int i = 0; i < nc; ++i) mx = fmaxf(mx, lw[i * 4 + t]);
            float sc = __expf(m_old - mx);           // 0 on first chunk
            float zz = shz[t] * sc;
            for (int i = 0; i < nc; ++i) {
                float w = __expf(lw[i * 4 + t] - mx);
                lw[i * 4 + t] = w;
                zz += w;
            }
            shm[t] = mx; shz[t] = zz; shscale[t] = sc;
        }
        __syncthreads();
        acc *= shscale[hd];
        #pragma unroll 4
        for (int i = 0; i < nc; ++i) {
            float w = lw[i * 4 + hd];
            acc += w * Hf[(size_t)lsrc[i] * 128 + t];
        }
        __syncthreads();
    }
    float res = skipagg[(size_t)d * 128 + t] + acc / shz[hd];
    outbuf[(size_t)d * 128 + t] = fmaxf(res, 0.f);
}

// ---------------- pooling + MLP ----------------
__global__ void pool_init(float* __restrict__ pooled) {
    int i = blockIdx.x * 256 + threadIdx.x;
    if (i < GGR * HCC) pooled[i] = -INFINITY;
}

__global__ void pool_max(const float* __restrict__ xf, const int* __restrict__ batch,
                         float* __restrict__ pooled)
{
    int i = blockIdx.x * 256 + threadIdx.x;
    if (i >= NN * HCC) return;
    int n = i >> 7, c = i & 127;
    atomicMaxF(&pooled[batch[n] * 128 + c], xf[i]);
}

__global__ __launch_bounds__(512) void mlp1(const float* __restrict__ pooled,
                                            const float* __restrict__ w,
                                            const float* __restrict__ bias,
                                            float* __restrict__ hid)
{
    __shared__ float xs[128];
    int g = blockIdx.x, t = threadIdx.x;
    if (t < 128) {
        float v = pooled[g * 128 + t];
        if (!isfinite(v)) v = 0.f;
        xs[t] = v;
    }
    __syncthreads();
    float acc = 0.f;
    #pragma unroll 8
    for (int k = 0; k < 128; ++k) acc += xs[k] * w[(size_t)k * NHIDD + t];
    hid[(size_t)g * NHIDD + t] = fmaxf(acc + bias[t], 0.f);
}

__global__ __launch_bounds__(768) void mlp2(const float* __restrict__ hid,
                                            const float* __restrict__ w,
                                            const float* __restrict__ bias,
                                            float* __restrict__ out)
{
    __shared__ float xs[NHIDD];
    int g = blockIdx.x, t = threadIdx.x;
    if (t < NHIDD) xs[t] = hid[(size_t)g * NHIDD + t];
    __syncthreads();
    float acc = 0.f;
    #pragma unroll 8
    for (int k = 0; k < NHIDD; ++k) acc += xs[k] * w[(size_t)k * NOUTD + t];
    out[(size_t)g * NOUTD + t] = acc + bias[t];
}

extern "C" void kernel_launch(void* const* d_in, const int* in_sizes, int n_in,
                              void* d_out, int out_size, void* d_ws, size_t ws_size,
                              hipStream_t stream)
{
    const float* x = (const float*)d_in[0];
    const int* ei = (const int*)d_in[1];
    const int* batch = (const int*)d_in[2];
    const float* W[3]   = {(const float*)d_in[3],  (const float*)d_in[9],  (const float*)d_in[15]};
    const float* AS[3]  = {(const float*)d_in[4],  (const float*)d_in[10], (const float*)d_in[16]};
    const float* AD[3]  = {(const float*)d_in[5],  (const float*)d_in[11], (const float*)d_in[17]};
    const float* B[3]   = {(const float*)d_in[6],  (const float*)d_in[12], (const float*)d_in[18]};
    const float* SKW[3] = {(const float*)d_in[7],  (const float*)d_in[13], (const float*)d_in[19]};
    const float* SKB[3] = {(const float*)d_in[8],  (const float*)d_in[14], (const float*)d_in[20]};
    const float* m1w = (const float*)d_in[21];
    const float* m1b = (const float*)d_in[22];
    const float* m2w = (const float*)d_in[23];
    const float* m2b = (const float*)d_in[24];
    float* out = (float*)d_out;

    float* p = (float*)d_ws;
    float* bufA = p; p += (size_t)NN * HCC;
    float* bufB = p; p += (size_t)NN * HCC;
    float* hbuf = p; p += (size_t)NN * HCC;
    float* agg  = p; p += (size_t)NN * HCC;
    float* esrc = p; p += NN * 4;
    float* edst = p; p += NN * 4;
    float* pooled = p; p += GGR * HCC;
    float* hidden = p; p += GGR * NHIDD;
    int* counts    = (int*)p; p += NN;
    int* row_start = (int*)p; p += NN + 4;
    int* cursor    = (int*)p; p += NN;
    int* csr_src   = (int*)p; p += EPE;

    // CSR build (dst-sorted edges), once per call
    hist_zero<<<(NN + 255) / 256, 256, 0, stream>>>(counts);
    hist<<<(EPE + 255) / 256, 256, 0, stream>>>(ei, counts);
    scan_rows<<<1, 1024, 0, stream>>>(counts, row_start, cursor);
    scatter_csr<<<(EPE + 255) / 256, 256, 0, stream>>>(ei, cursor, csr_src);

    const float* cur = x;
    float* outs[3] = {bufA, bufB, bufA};
    for (int l = 0; l < 3; ++l) {
        dim3 gg((NN + 63) / 64, 4);
        gemm_node<<<gg, 256, 0, stream>>>(cur, W[l], SKW[l], SKB[l], B[l], hbuf, agg);
        node_attn<<<NN / 2, 256, 0, stream>>>(hbuf, AS[l], AD[l], esrc, edst);
        gat_aggr<<<NN, 128, 0, stream>>>(row_start, csr_src, esrc, edst, hbuf, agg, outs[l]);
        cur = outs[l];
    }
    pool_init<<<(GGR * HCC) / 256, 256, 0, stream>>>(pooled);
    pool_max<<<(NN * HCC + 255) / 256, 256, 0, stream>>>(cur, batch, pooled);
    mlp1<<<GGR, NHIDD, 0, stream>>>(pooled, m1w, m1b, hidden);
    mlp2<<<GGR, NOUTD, 0, stream>>>(hidden, m2w, m2b, out);
}

// Round 3
// 721.500 us; speedup vs baseline: 3.3365x; 1.1221x over previous
//
#include <hip/hip_runtime.h>
#include <hip/hip_bf16.h>
#include <math.h>

#define NN 50000
#define EE 800000
#define EPE 850000   // EE + NN self loops
#define HCC 128
#define GGR 256
#define NHIDD 512
#define NOUTD 768
#define CHUNK 256
#define SCAN_NBLK ((NN + 1023) / 1024)   // 49

__device__ __forceinline__ void atomicMaxF(float* addr, float v) {
    if (v >= 0.f) atomicMax(reinterpret_cast<int*>(addr), __float_as_int(v));
    else atomicMin(reinterpret_cast<unsigned int*>(addr), __float_as_uint(v));
}

__device__ __forceinline__ float lrelu(float x) { return x > 0.f ? x : 0.2f * x; }

// ---------------- CSR build (once per call) ----------------
__global__ void hist_zero(int* __restrict__ counts) {
    int i = blockIdx.x * 256 + threadIdx.x;
    if (i < NN) counts[i] = 0;
}

__global__ void hist(const int* __restrict__ ei, int* __restrict__ counts) {
    int e = blockIdx.x * 256 + threadIdx.x;
    if (e >= EPE) return;
    int d = (e < EE) ? ei[EE + e] : e - EE;
    atomicAdd(&counts[d], 1);
}

// stage 1: per-block (1024 elements) exclusive scan + block sums
__global__ __launch_bounds__(256) void scan_partial(const int* __restrict__ counts,
                                                    int* __restrict__ excl,
                                                    int* __restrict__ blocksums)
{
    __shared__ int s[256];
    const int b = blockIdx.x, t = threadIdx.x;
    const int idx = b * 1024 + t * 4;
    int a0 = (idx + 0 < NN) ? counts[idx + 0] : 0;
    int a1 = (idx + 1 < NN) ? counts[idx + 1] : 0;
    int a2 = (idx + 2 < NN) ? counts[idx + 2] : 0;
    int a3 = (idx + 3 < NN) ? counts[idx + 3] : 0;
    int sum4 = a0 + a1 + a2 + a3;
    s[t] = sum4;
    __syncthreads();
    #pragma unroll
    for (int off = 1; off < 256; off <<= 1) {
        int add = (t >= off) ? s[t - off] : 0;
        __syncthreads();
        s[t] += add;
        __syncthreads();
    }
    int e0 = s[t] - sum4;
    if (idx + 0 < NN) excl[idx + 0] = e0;
    if (idx + 1 < NN) excl[idx + 1] = e0 + a0;
    if (idx + 2 < NN) excl[idx + 2] = e0 + a0 + a1;
    if (idx + 3 < NN) excl[idx + 3] = e0 + a0 + a1 + a2;
    if (t == 255) blocksums[b] = s[255];
}

// stage 2: scan the 49 block sums; also write row_start[NN] = total
__global__ __launch_bounds__(64) void scan_sums(int* __restrict__ blocksums,
                                                int* __restrict__ blockoffs,
                                                int* __restrict__ row_start)
{
    __shared__ int s[64];
    int t = threadIdx.x;
    int v = (t < SCAN_NBLK) ? blocksums[t] : 0;
    s[t] = v;
    __syncthreads();
    #pragma unroll
    for (int off = 1; off < 64; off <<= 1) {
        int add = (t >= off) ? s[t - off] : 0;
        __syncthreads();
        s[t] += add;
        __syncthreads();
    }
    if (t < SCAN_NBLK) blockoffs[t] = s[t] - v;
    if (t == 63) row_start[NN] = s[63];
}

// stage 3: add block offsets -> row_start, cursor
__global__ void scan_add(const int* __restrict__ excl, const int* __restrict__ blockoffs,
                         int* __restrict__ row_start, int* __restrict__ cursor)
{
    int i = blockIdx.x * 256 + threadIdx.x;
    if (i >= NN) return;
    int v = excl[i] + blockoffs[i >> 10];
    row_start[i] = v;
    cursor[i] = v;
}

__global__ void scatter_csr(const int* __restrict__ ei, int* __restrict__ cursor,
                            int* __restrict__ csr_src) {
    int e = blockIdx.x * 256 + threadIdx.x;
    if (e >= EPE) return;
    int s, d;
    if (e < EE) { s = ei[e]; d = ei[EE + e]; } else { s = d = e - EE; }
    int pos = atomicAdd(&cursor[d], 1);
    csr_src[pos] = s;
}

// ---------------- node GEMM (h and skip) ----------------
__global__ __launch_bounds__(256) void gemm_node(
    const float* __restrict__ X, const float* __restrict__ W, const float* __restrict__ SKW,
    const float* __restrict__ skb, const float* __restrict__ bb,
    float* __restrict__ Hout, float* __restrict__ Agg)
{
    __shared__ float Xs[128][68];   // [k][m]
    __shared__ float Ws[128][68];   // [k][c]
    const int row0 = blockIdx.x * 64;
    const int bc = blockIdx.y;                 // 0..3
    const int tid = threadIdx.x;
    const float* M = (bc < 2) ? W : SKW;
    const int colOff = (bc & 1) * 64;

    {
        int m = tid >> 2;
        int kq = (tid & 3) * 4;
        int n = row0 + m;
        #pragma unroll
        for (int it = 0; it < 8; ++it) {
            int k = kq + it * 16;
            float4 v = make_float4(0.f, 0.f, 0.f, 0.f);
            if (n < NN) v = *reinterpret_cast<const float4*>(X + (size_t)n * 128 + k);
            Xs[k + 0][m] = v.x; Xs[k + 1][m] = v.y; Xs[k + 2][m] = v.z; Xs[k + 3][m] = v.w;
        }
    }
    {
        int kr = tid >> 4;
        int c4 = (tid & 15) * 4;
        #pragma unroll
        for (int it = 0; it < 8; ++it) {
            int k = it * 16 + kr;
            float4 v = *reinterpret_cast<const float4*>(M + (size_t)k * 128 + colOff + c4);
            *reinterpret_cast<float4*>(&Ws[k][c4]) = v;
        }
    }
    __syncthreads();

    const int tx = tid & 15, ty = tid >> 4;
    float acc[4][4] = {};
    #pragma unroll 4
    for (int k = 0; k < 128; ++k) {
        float4 a = *reinterpret_cast<const float4*>(&Xs[k][ty * 4]);
        float4 b = *reinterpret_cast<const float4*>(&Ws[k][tx * 4]);
        float av[4] = {a.x, a.y, a.z, a.w};
        float bv[4] = {b.x, b.y, b.z, b.w};
        #pragma unroll
        for (int i = 0; i < 4; ++i) {
            #pragma unroll
            for (int j = 0; j < 4; ++j) acc[i][j] += av[i] * bv[j];
        }
    }

    #pragma unroll
    for (int i = 0; i < 4; ++i) {
        int n = row0 + ty * 4 + i;
        if (n >= NN) continue;
        int c = colOff + tx * 4;
        if (bc < 2) {
            float4 v = make_float4(acc[i][0], acc[i][1], acc[i][2], acc[i][3]);
            *reinterpret_cast<float4*>(Hout + (size_t)n * 128 + c) = v;
        } else {
            float4 v;
            v.x = acc[i][0] + skb[c + 0] + bb[c + 0];
            v.y = acc[i][1] + skb[c + 1] + bb[c + 1];
            v.z = acc[i][2] + skb[c + 2] + bb[c + 2];
            v.w = acc[i][3] + skb[c + 3] + bb[c + 3];
            *reinterpret_cast<float4*>(Agg + (size_t)n * 128 + c) = v;
        }
    }
}

// per-node attention coefficients e_src/e_dst [N,4]
__global__ __launch_bounds__(256) void node_attn(
    const float* __restrict__ Hf, const float* __restrict__ as_, const float* __restrict__ ad_,
    float* __restrict__ esrc, float* __restrict__ edst)
{
    int tid = threadIdx.x;
    int node = blockIdx.x * 2 + (tid >> 7);
    int t = tid & 127;
    if (node >= NN) return;
    float hv = Hf[(size_t)node * 128 + t];
    float p1 = hv * as_[t];
    float p2 = hv * ad_[t];
    #pragma unroll
    for (int o = 16; o > 0; o >>= 1) {
        p1 += __shfl_down(p1, o, 32);
        p2 += __shfl_down(p2, o, 32);
    }
    if ((t & 31) == 0) {
        esrc[node * 4 + (t >> 5)] = p1;
        edst[node * 4 + (t >> 5)] = p2;
    }
}

// ---------------- fused per-dst softmax + aggregate + skip + relu ----------------
__global__ __launch_bounds__(128) void gat_aggr(
    const int* __restrict__ row_start, const int* __restrict__ csr_src,
    const float* __restrict__ esrc, const float* __restrict__ edst,
    const float* __restrict__ Hf, const float* __restrict__ skipagg,
    float* __restrict__ outbuf)
{
    __shared__ int   lsrc[CHUNK];
    __shared__ float lw[CHUNK * 4];
    __shared__ float shm[4], shz[4], shscale[4];
    const int d = blockIdx.x;
    const int t = threadIdx.x;
    const int hd = t >> 5;
    const int r0 = row_start[d], r1 = row_start[d + 1];
    const float4 edv = *reinterpret_cast<const float4*>(edst + (size_t)d * 4);
    float acc = 0.f;
    if (t < 4) { shm[t] = -INFINITY; shz[t] = 0.f; }
    __syncthreads();

    for (int base = r0; base < r1; base += CHUNK) {
        const int nc = min(CHUNK, r1 - base);
        for (int i = t; i < nc; i += 128) {
            int s = csr_src[base + i];
            lsrc[i] = s;
            float4 ev = *reinterpret_cast<const float4*>(esrc + (size_t)s * 4);
            lw[i * 4 + 0] = lrelu(ev.x + edv.x);
            lw[i * 4 + 1] = lrelu(ev.y + edv.y);
            lw[i * 4 + 2] = lrelu(ev.z + edv.z);
            lw[i * 4 + 3] = lrelu(ev.w + edv.w);
        }
        __syncthreads();
        if (t < 4) {
            float m_old = shm[t];
            float mx = m_old;
            for (int i = 0; i < nc; ++i) mx = fmaxf(mx, lw[i * 4 + t]);
            float sc = __expf(m_old - mx);           // 0 on first chunk
            float zz = shz[t] * sc;
            for (int i = 0; i < nc; ++i) {
                float w = __expf(lw[i * 4 + t] - mx);
                lw[i * 4 + t] = w;
                zz += w;
            }
            shm[t] = mx; shz[t] = zz; shscale[t] = sc;
        }
        __syncthreads();
        acc *= shscale[hd];
        #pragma unroll 4
        for (int i = 0; i < nc; ++i) {
            float w = lw[i * 4 + hd];
            acc += w * Hf[(size_t)lsrc[i] * 128 + t];
        }
        __syncthreads();
    }
    float res = skipagg[(size_t)d * 128 + t] + acc / shz[hd];
    outbuf[(size_t)d * 128 + t] = fmaxf(res, 0.f);
}

// ---------------- pooling + MLP ----------------
__global__ void pool_init(float* __restrict__ pooled) {
    int i = blockIdx.x * 256 + threadIdx.x;
    if (i < GGR * HCC) pooled[i] = -INFINITY;
}

__global__ void pool_max(const float* __restrict__ xf, const int* __restrict__ batch,
                         float* __restrict__ pooled)
{
    int i = blockIdx.x * 256 + threadIdx.x;
    if (i >= NN * HCC) return;
    int n = i >> 7, c = i & 127;
    atomicMaxF(&pooled[batch[n] * 128 + c], xf[i]);
}

__global__ __launch_bounds__(512) void mlp1(const float* __restrict__ pooled,
                                            const float* __restrict__ w,
                                            const float* __restrict__ bias,
                                            float* __restrict__ hid)
{
    __shared__ float xs[128];
    int g = blockIdx.x, t = threadIdx.x;
    if (t < 128) {
        float v = pooled[g * 128 + t];
        if (!isfinite(v)) v = 0.f;
        xs[t] = v;
    }
    __syncthreads();
    float acc = 0.f;
    #pragma unroll 8
    for (int k = 0; k < 128; ++k) acc += xs[k] * w[(size_t)k * NHIDD + t];
    hid[(size_t)g * NHIDD + t] = fmaxf(acc + bias[t], 0.f);
}

__global__ __launch_bounds__(768) void mlp2(const float* __restrict__ hid,
                                            const float* __restrict__ w,
                                            const float* __restrict__ bias,
                                            float* __restrict__ out)
{
    __shared__ float xs[NHIDD];
    int g = blockIdx.x, t = threadIdx.x;
    if (t < NHIDD) xs[t] = hid[(size_t)g * NHIDD + t];
    __syncthreads();
    float acc = 0.f;
    #pragma unroll 8
    for (int k = 0; k < NHIDD; ++k) acc += xs[k] * w[(size_t)k * NOUTD + t];
    out[(size_t)g * NOUTD + t] = acc + bias[t];
}

extern "C" void kernel_launch(void* const* d_in, const int* in_sizes, int n_in,
                              void* d_out, int out_size, void* d_ws, size_t ws_size,
                              hipStream_t stream)
{
    const float* x = (const float*)d_in[0];
    const int* ei = (const int*)d_in[1];
    const int* batch = (const int*)d_in[2];
    const float* W[3]   = {(const float*)d_in[3],  (const float*)d_in[9],  (const float*)d_in[15]};
    const float* AS[3]  = {(const float*)d_in[4],  (const float*)d_in[10], (const float*)d_in[16]};
    const float* AD[3]  = {(const float*)d_in[5],  (const float*)d_in[11], (const float*)d_in[17]};
    const float* B[3]   = {(const float*)d_in[6],  (const float*)d_in[12], (const float*)d_in[18]};
    const float* SKW[3] = {(const float*)d_in[7],  (const float*)d_in[13], (const float*)d_in[19]};
    const float* SKB[3] = {(const float*)d_in[8],  (const float*)d_in[14], (const float*)d_in[20]};
    const float* m1w = (const float*)d_in[21];
    const float* m1b = (const float*)d_in[22];
    const float* m2w = (const float*)d_in[23];
    const float* m2b = (const float*)d_in[24];
    float* out = (float*)d_out;

    float* p = (float*)d_ws;
    float* bufA = p; p += (size_t)NN * HCC;
    float* bufB = p; p += (size_t)NN * HCC;
    float* hbuf = p; p += (size_t)NN * HCC;
    float* agg  = p; p += (size_t)NN * HCC;
    float* esrc = p; p += NN * 4;
    float* edst = p; p += NN * 4;
    float* pooled = p; p += GGR * HCC;
    float* hidden = p; p += GGR * NHIDD;
    int* counts    = (int*)p; p += NN;
    int* excl      = (int*)p; p += NN;
    int* row_start = (int*)p; p += NN + 4;
    int* cursor    = (int*)p; p += NN;
    int* csr_src   = (int*)p; p += EPE;
    int* blocksums = (int*)p; p += 64;
    int* blockoffs = (int*)p; p += 64;

    // CSR build (dst-sorted edges), once per call
    hist_zero<<<(NN + 255) / 256, 256, 0, stream>>>(counts);
    hist<<<(EPE + 255) / 256, 256, 0, stream>>>(ei, counts);
    scan_partial<<<SCAN_NBLK, 256, 0, stream>>>(counts, excl, blocksums);
    scan_sums<<<1, 64, 0, stream>>>(blocksums, blockoffs, row_start);
    scan_add<<<(NN + 255) / 256, 256, 0, stream>>>(excl, blockoffs, row_start, cursor);
    scatter_csr<<<(EPE + 255) / 256, 256, 0, stream>>>(ei, cursor, csr_src);

    const float* cur = x;
    float* outs[3] = {bufA, bufB, bufA};
    for (int l = 0; l < 3; ++l) {
        dim3 gg((NN + 63) / 64, 4);
        gemm_node<<<gg, 256, 0, stream>>>(cur, W[l], SKW[l], SKB[l], B[l], hbuf, agg);
        node_attn<<<NN / 2, 256, 0, stream>>>(hbuf, AS[l], AD[l], esrc, edst);
        gat_aggr<<<NN, 128, 0, stream>>>(row_start, csr_src, esrc, edst, hbuf, agg, outs[l]);
        cur = outs[l];
    }
    pool_init<<<(GGR * HCC) / 256, 256, 0, stream>>>(pooled);
    pool_max<<<(NN * HCC + 255) / 256, 256, 0, stream>>>(cur, batch, pooled);
    mlp1<<<GGR, NHIDD, 0, stream>>>(pooled, m1w, m1b, hidden);
    mlp2<<<GGR, NOUTD, 0, stream>>>(hidden, m2w, m2b, out);
}

// Round 4
// 697.985 us; speedup vs baseline: 3.4489x; 1.0337x over previous
//
#include <hip/hip_runtime.h>
#include <hip/hip_bf16.h>
#include <math.h>

#define NN 50000
#define EE 800000
#define EPE 850000   // EE + NN self loops
#define HCC 128
#define GGR 256
#define NHIDD 512
#define NOUTD 768
#define CHUNK 256
#define SCAN_NBLK ((NN + 1023) / 1024)   // 49

__device__ __forceinline__ void atomicMaxF(float* addr, float v) {
    if (v >= 0.f) atomicMax(reinterpret_cast<int*>(addr), __float_as_int(v));
    else atomicMin(reinterpret_cast<unsigned int*>(addr), __float_as_uint(v));
}

__device__ __forceinline__ float lrelu(float x) { return x > 0.f ? x : 0.2f * x; }

__device__ __forceinline__ ushort f2bf(float f) {
    unsigned u = __float_as_uint(f);
    unsigned r = (u + 0x7fffu + ((u >> 16) & 1u)) >> 16;   // RNE
    return (ushort)r;
}
__device__ __forceinline__ float bf2f(ushort b) {
    return __uint_as_float(((unsigned)b) << 16);
}

// ---------------- CSR build (once per call) ----------------
__global__ void hist_zero(int* __restrict__ counts) {
    int i = blockIdx.x * 256 + threadIdx.x;
    if (i < NN) counts[i] = 0;
}

__global__ void hist(const int* __restrict__ ei, int* __restrict__ counts) {
    int e = blockIdx.x * 256 + threadIdx.x;
    if (e >= EPE) return;
    int d = (e < EE) ? ei[EE + e] : e - EE;
    atomicAdd(&counts[d], 1);
}

__global__ __launch_bounds__(256) void scan_partial(const int* __restrict__ counts,
                                                    int* __restrict__ excl,
                                                    int* __restrict__ blocksums)
{
    __shared__ int s[256];
    const int b = blockIdx.x, t = threadIdx.x;
    const int idx = b * 1024 + t * 4;
    int a0 = (idx + 0 < NN) ? counts[idx + 0] : 0;
    int a1 = (idx + 1 < NN) ? counts[idx + 1] : 0;
    int a2 = (idx + 2 < NN) ? counts[idx + 2] : 0;
    int a3 = (idx + 3 < NN) ? counts[idx + 3] : 0;
    int sum4 = a0 + a1 + a2 + a3;
    s[t] = sum4;
    __syncthreads();
    #pragma unroll
    for (int off = 1; off < 256; off <<= 1) {
        int add = (t >= off) ? s[t - off] : 0;
        __syncthreads();
        s[t] += add;
        __syncthreads();
    }
    int e0 = s[t] - sum4;
    if (idx + 0 < NN) excl[idx + 0] = e0;
    if (idx + 1 < NN) excl[idx + 1] = e0 + a0;
    if (idx + 2 < NN) excl[idx + 2] = e0 + a0 + a1;
    if (idx + 3 < NN) excl[idx + 3] = e0 + a0 + a1 + a2;
    if (t == 255) blocksums[b] = s[255];
}

__global__ __launch_bounds__(64) void scan_sums(int* __restrict__ blocksums,
                                                int* __restrict__ blockoffs,
                                                int* __restrict__ row_start)
{
    __shared__ int s[64];
    int t = threadIdx.x;
    int v = (t < SCAN_NBLK) ? blocksums[t] : 0;
    s[t] = v;
    __syncthreads();
    #pragma unroll
    for (int off = 1; off < 64; off <<= 1) {
        int add = (t >= off) ? s[t - off] : 0;
        __syncthreads();
        s[t] += add;
        __syncthreads();
    }
    if (t < SCAN_NBLK) blockoffs[t] = s[t] - v;
    if (t == 63) row_start[NN] = s[63];
}

__global__ void scan_add(const int* __restrict__ excl, const int* __restrict__ blockoffs,
                         int* __restrict__ row_start, int* __restrict__ cursor)
{
    int i = blockIdx.x * 256 + threadIdx.x;
    if (i >= NN) return;
    int v = excl[i] + blockoffs[i >> 10];
    row_start[i] = v;
    cursor[i] = v;
}

__global__ void scatter_csr(const int* __restrict__ ei, int* __restrict__ cursor,
                            int* __restrict__ csr_src) {
    int e = blockIdx.x * 256 + threadIdx.x;
    if (e >= EPE) return;
    int s, d;
    if (e < EE) { s = ei[e]; d = ei[EE + e]; } else { s = d = e - EE; }
    int pos = atomicAdd(&cursor[d], 1);
    csr_src[pos] = s;
}

// ---------------- node GEMM (h -> bf16, skip -> fp32) ----------------
__global__ __launch_bounds__(256) void gemm_node(
    const float* __restrict__ X, const float* __restrict__ W, const float* __restrict__ SKW,
    const float* __restrict__ skb, const float* __restrict__ bb,
    ushort* __restrict__ Hout, float* __restrict__ Agg)
{
    __shared__ float Xs[128][68];   // [k][m]
    __shared__ float Ws[128][68];   // [k][c]
    const int row0 = blockIdx.x * 64;
    const int bc = blockIdx.y;                 // 0..3
    const int tid = threadIdx.x;
    const float* M = (bc < 2) ? W : SKW;
    const int colOff = (bc & 1) * 64;

    {
        int m = tid >> 2;
        int kq = (tid & 3) * 4;
        int n = row0 + m;
        #pragma unroll
        for (int it = 0; it < 8; ++it) {
            int k = kq + it * 16;
            float4 v = make_float4(0.f, 0.f, 0.f, 0.f);
            if (n < NN) v = *reinterpret_cast<const float4*>(X + (size_t)n * 128 + k);
            Xs[k + 0][m] = v.x; Xs[k + 1][m] = v.y; Xs[k + 2][m] = v.z; Xs[k + 3][m] = v.w;
        }
    }
    {
        int kr = tid >> 4;
        int c4 = (tid & 15) * 4;
        #pragma unroll
        for (int it = 0; it < 8; ++it) {
            int k = it * 16 + kr;
            float4 v = *reinterpret_cast<const float4*>(M + (size_t)k * 128 + colOff + c4);
            *reinterpret_cast<float4*>(&Ws[k][c4]) = v;
        }
    }
    __syncthreads();

    const int tx = tid & 15, ty = tid >> 4;
    float acc[4][4] = {};
    #pragma unroll 4
    for (int k = 0; k < 128; ++k) {
        float4 a = *reinterpret_cast<const float4*>(&Xs[k][ty * 4]);
        float4 b = *reinterpret_cast<const float4*>(&Ws[k][tx * 4]);
        float av[4] = {a.x, a.y, a.z, a.w};
        float bv[4] = {b.x, b.y, b.z, b.w};
        #pragma unroll
        for (int i = 0; i < 4; ++i) {
            #pragma unroll
            for (int j = 0; j < 4; ++j) acc[i][j] += av[i] * bv[j];
        }
    }

    #pragma unroll
    for (int i = 0; i < 4; ++i) {
        int n = row0 + ty * 4 + i;
        if (n >= NN) continue;
        int c = colOff + tx * 4;
        if (bc < 2) {
            ushort4 v;
            v.x = f2bf(acc[i][0]); v.y = f2bf(acc[i][1]);
            v.z = f2bf(acc[i][2]); v.w = f2bf(acc[i][3]);
            *reinterpret_cast<ushort4*>(Hout + (size_t)n * 128 + c) = v;
        } else {
            float4 v;
            v.x = acc[i][0] + skb[c + 0] + bb[c + 0];
            v.y = acc[i][1] + skb[c + 1] + bb[c + 1];
            v.z = acc[i][2] + skb[c + 2] + bb[c + 2];
            v.w = acc[i][3] + skb[c + 3] + bb[c + 3];
            *reinterpret_cast<float4*>(Agg + (size_t)n * 128 + c) = v;
        }
    }
}

// per-node attention coefficients e_src/e_dst [N,4] (bf16 h input)
__global__ __launch_bounds__(256) void node_attn(
    const ushort* __restrict__ Hb, const float* __restrict__ as_, const float* __restrict__ ad_,
    float* __restrict__ esrc, float* __restrict__ edst)
{
    int tid = threadIdx.x;
    int node = blockIdx.x * 2 + (tid >> 7);
    int t = tid & 127;
    if (node >= NN) return;
    float hv = bf2f(Hb[(size_t)node * 128 + t]);
    float p1 = hv * as_[t];
    float p2 = hv * ad_[t];
    #pragma unroll
    for (int o = 16; o > 0; o >>= 1) {
        p1 += __shfl_down(p1, o, 32);
        p2 += __shfl_down(p2, o, 32);
    }
    if ((t & 31) == 0) {
        esrc[node * 4 + (t >> 5)] = p1;
        edst[node * 4 + (t >> 5)] = p2;
    }
}

// ---------------- fused per-dst softmax + aggregate + skip + relu ----------------
__global__ __launch_bounds__(128) void gat_aggr(
    const int* __restrict__ row_start, const int* __restrict__ csr_src,
    const float* __restrict__ esrc, const float* __restrict__ edst,
    const ushort* __restrict__ Hb, const float* __restrict__ skipagg,
    float* __restrict__ outbuf)
{
    __shared__ int   lsrc[CHUNK];
    __shared__ float lw[CHUNK * 4];
    __shared__ float shm[4], shz[4], shscale[4];
    const int d = blockIdx.x;
    const int t = threadIdx.x;
    const int hd = t >> 5;
    const int r0 = row_start[d], r1 = row_start[d + 1];
    const float4 edv = *reinterpret_cast<const float4*>(edst + (size_t)d * 4);
    float acc = 0.f;
    if (t < 4) { shm[t] = -INFINITY; shz[t] = 0.f; }
    __syncthreads();

    for (int base = r0; base < r1; base += CHUNK) {
        const int nc = min(CHUNK, r1 - base);
        for (int i = t; i < nc; i += 128) {
            int s = csr_src[base + i];
            lsrc[i] = s;
            float4 ev = *reinterpret_cast<const float4*>(esrc + (size_t)s * 4);
            lw[i * 4 + 0] = lrelu(ev.x + edv.x);
            lw[i * 4 + 1] = lrelu(ev.y + edv.y);
            lw[i * 4 + 2] = lrelu(ev.z + edv.z);
            lw[i * 4 + 3] = lrelu(ev.w + edv.w);
        }
        __syncthreads();
        if (t < 4) {
            float m_old = shm[t];
            float mx = m_old;
            for (int i = 0; i < nc; ++i) mx = fmaxf(mx, lw[i * 4 + t]);
            float sc = __expf(m_old - mx);           // 0 on first chunk
            float zz = shz[t] * sc;
            for (int i = 0; i < nc; ++i) {
                float w = __expf(lw[i * 4 + t] - mx);
                lw[i * 4 + t] = w;
                zz += w;
            }
            shm[t] = mx; shz[t] = zz; shscale[t] = sc;
        }
        __syncthreads();
        acc *= shscale[hd];
        #pragma unroll 4
        for (int i = 0; i < nc; ++i) {
            float w = lw[i * 4 + hd];
            acc += w * bf2f(Hb[(size_t)lsrc[i] * 128 + t]);
        }
        __syncthreads();
    }
    float res = skipagg[(size_t)d * 128 + t] + acc / shz[hd];
    outbuf[(size_t)d * 128 + t] = fmaxf(res, 0.f);
}

// ---------------- pooling + MLP ----------------
__global__ void pool_init(float* __restrict__ pooled) {
    int i = blockIdx.x * 256 + threadIdx.x;
    if (i < GGR * HCC) pooled[i] = -INFINITY;
}

__global__ void pool_max(const float* __restrict__ xf, const int* __restrict__ batch,
                         float* __restrict__ pooled)
{
    int i = blockIdx.x * 256 + threadIdx.x;
    if (i >= NN * HCC) return;
    int n = i >> 7, c = i & 127;
    atomicMaxF(&pooled[batch[n] * 128 + c], xf[i]);
}

__global__ __launch_bounds__(512) void mlp1(const float* __restrict__ pooled,
                                            const float* __restrict__ w,
                                            const float* __restrict__ bias,
                                            float* __restrict__ hid)
{
    __shared__ float xs[128];
    int g = blockIdx.x, t = threadIdx.x;
    if (t < 128) {
        float v = pooled[g * 128 + t];
        if (!isfinite(v)) v = 0.f;
        xs[t] = v;
    }
    __syncthreads();
    float acc = 0.f;
    #pragma unroll 8
    for (int k = 0; k < 128; ++k) acc += xs[k] * w[(size_t)k * NHIDD + t];
    hid[(size_t)g * NHIDD + t] = fmaxf(acc + bias[t], 0.f);
}

__global__ __launch_bounds__(768) void mlp2(const float* __restrict__ hid,
                                            const float* __restrict__ w,
                                            const float* __restrict__ bias,
                                            float* __restrict__ out)
{
    __shared__ float xs[NHIDD];
    int g = blockIdx.x, t = threadIdx.x;
    if (t < NHIDD) xs[t] = hid[(size_t)g * NHIDD + t];
    __syncthreads();
    float acc = 0.f;
    #pragma unroll 8
    for (int k = 0; k < NHIDD; ++k) acc += xs[k] * w[(size_t)k * NOUTD + t];
    out[(size_t)g * NOUTD + t] = acc + bias[t];
}

extern "C" void kernel_launch(void* const* d_in, const int* in_sizes, int n_in,
                              void* d_out, int out_size, void* d_ws, size_t ws_size,
                              hipStream_t stream)
{
    const float* x = (const float*)d_in[0];
    const int* ei = (const int*)d_in[1];
    const int* batch = (const int*)d_in[2];
    const float* W[3]   = {(const float*)d_in[3],  (const float*)d_in[9],  (const float*)d_in[15]};
    const float* AS[3]  = {(const float*)d_in[4],  (const float*)d_in[10], (const float*)d_in[16]};
    const float* AD[3]  = {(const float*)d_in[5],  (const float*)d_in[11], (const float*)d_in[17]};
    const float* B[3]   = {(const float*)d_in[6],  (const float*)d_in[12], (const float*)d_in[18]};
    const float* SKW[3] = {(const float*)d_in[7],  (const float*)d_in[13], (const float*)d_in[19]};
    const float* SKB[3] = {(const float*)d_in[8],  (const float*)d_in[14], (const float*)d_in[20]};
    const float* m1w = (const float*)d_in[21];
    const float* m1b = (const float*)d_in[22];
    const float* m2w = (const float*)d_in[23];
    const float* m2b = (const float*)d_in[24];
    float* out = (float*)d_out;

    float* p = (float*)d_ws;
    float* bufA = p; p += (size_t)NN * HCC;
    float* bufB = p; p += (size_t)NN * HCC;
    ushort* hbuf = (ushort*)p; p += (size_t)NN * HCC / 2;
    float* agg  = p; p += (size_t)NN * HCC;
    float* esrc = p; p += NN * 4;
    float* edst = p; p += NN * 4;
    float* pooled = p; p += GGR * HCC;
    float* hidden = p; p += GGR * NHIDD;
    int* counts    = (int*)p; p += NN;
    int* excl      = (int*)p; p += NN;
    int* row_start = (int*)p; p += NN + 4;
    int* cursor    = (int*)p; p += NN;
    int* csr_src   = (int*)p; p += EPE;
    int* blocksums = (int*)p; p += 64;
    int* blockoffs = (int*)p; p += 64;

    // CSR build (dst-sorted edges), once per call
    hist_zero<<<(NN + 255) / 256, 256, 0, stream>>>(counts);
    hist<<<(EPE + 255) / 256, 256, 0, stream>>>(ei, counts);
    scan_partial<<<SCAN_NBLK, 256, 0, stream>>>(counts, excl, blocksums);
    scan_sums<<<1, 64, 0, stream>>>(blocksums, blockoffs, row_start);
    scan_add<<<(NN + 255) / 256, 256, 0, stream>>>(excl, blockoffs, row_start, cursor);
    scatter_csr<<<(EPE + 255) / 256, 256, 0, stream>>>(ei, cursor, csr_src);

    const float* cur = x;
    float* outs[3] = {bufA, bufB, bufA};
    for (int l = 0; l < 3; ++l) {
        dim3 gg((NN + 63) / 64, 4);
        gemm_node<<<gg, 256, 0, stream>>>(cur, W[l], SKW[l], SKB[l], B[l], hbuf, agg);
        node_attn<<<NN / 2, 256, 0, stream>>>(hbuf, AS[l], AD[l], esrc, edst);
        gat_aggr<<<NN, 128, 0, stream>>>(row_start, csr_src, esrc, edst, hbuf, agg, outs[l]);
        cur = outs[l];
    }
    pool_init<<<(GGR * HCC) / 256, 256, 0, stream>>>(pooled);
    pool_max<<<(NN * HCC + 255) / 256, 256, 0, stream>>>(cur, batch, pooled);
    mlp1<<<GGR, NHIDD, 0, stream>>>(pooled, m1w, m1b, hidden);
    mlp2<<<GGR, NOUTD, 0, stream>>>(hidden, m2w, m2b, out);
}

// Round 5
// 656.210 us; speedup vs baseline: 3.6685x; 1.0637x over previous
//
#include <hip/hip_runtime.h>
#include <hip/hip_bf16.h>
#include <math.h>

#define NN 50000
#define EE 800000
#define EPE 850000   // EE + NN self loops
#define HCC 128
#define GGR 256
#define NHIDD 512
#define NOUTD 768
#define CHUNK 256
#define SCAN_NBLK ((NN + 1023) / 1024)   // 49

__device__ __forceinline__ void atomicMaxF(float* addr, float v) {
    if (v >= 0.f) atomicMax(reinterpret_cast<int*>(addr), __float_as_int(v));
    else atomicMin(reinterpret_cast<unsigned int*>(addr), __float_as_uint(v));
}

__device__ __forceinline__ float lrelu(float x) { return x > 0.f ? x : 0.2f * x; }

__device__ __forceinline__ ushort f2bf(float f) {
    unsigned u = __float_as_uint(f);
    unsigned r = (u + 0x7fffu + ((u >> 16) & 1u)) >> 16;   // RNE
    return (ushort)r;
}
__device__ __forceinline__ float bf2f(ushort b) {
    return __uint_as_float(((unsigned)b) << 16);
}

// ---------------- CSR build (once per call) ----------------
__global__ void hist_zero(int* __restrict__ counts) {
    int i = blockIdx.x * 256 + threadIdx.x;
    if (i < NN) counts[i] = 0;
}

__global__ void hist(const int* __restrict__ ei, int* __restrict__ counts) {
    int e = blockIdx.x * 256 + threadIdx.x;
    if (e >= EPE) return;
    int d = (e < EE) ? ei[EE + e] : e - EE;
    atomicAdd(&counts[d], 1);
}

__global__ __launch_bounds__(256) void scan_partial(const int* __restrict__ counts,
                                                    int* __restrict__ excl,
                                                    int* __restrict__ blocksums)
{
    __shared__ int s[256];
    const int b = blockIdx.x, t = threadIdx.x;
    const int idx = b * 1024 + t * 4;
    int a0 = (idx + 0 < NN) ? counts[idx + 0] : 0;
    int a1 = (idx + 1 < NN) ? counts[idx + 1] : 0;
    int a2 = (idx + 2 < NN) ? counts[idx + 2] : 0;
    int a3 = (idx + 3 < NN) ? counts[idx + 3] : 0;
    int sum4 = a0 + a1 + a2 + a3;
    s[t] = sum4;
    __syncthreads();
    #pragma unroll
    for (int off = 1; off < 256; off <<= 1) {
        int add = (t >= off) ? s[t - off] : 0;
        __syncthreads();
        s[t] += add;
        __syncthreads();
    }
    int e0 = s[t] - sum4;
    if (idx + 0 < NN) excl[idx + 0] = e0;
    if (idx + 1 < NN) excl[idx + 1] = e0 + a0;
    if (idx + 2 < NN) excl[idx + 2] = e0 + a0 + a1;
    if (idx + 3 < NN) excl[idx + 3] = e0 + a0 + a1 + a2;
    if (t == 255) blocksums[b] = s[255];
}

__global__ __launch_bounds__(64) void scan_sums(int* __restrict__ blocksums,
                                                int* __restrict__ blockoffs,
                                                int* __restrict__ row_start)
{
    __shared__ int s[64];
    int t = threadIdx.x;
    int v = (t < SCAN_NBLK) ? blocksums[t] : 0;
    s[t] = v;
    __syncthreads();
    #pragma unroll
    for (int off = 1; off < 64; off <<= 1) {
        int add = (t >= off) ? s[t - off] : 0;
        __syncthreads();
        s[t] += add;
        __syncthreads();
    }
    if (t < SCAN_NBLK) blockoffs[t] = s[t] - v;
    if (t == 63) row_start[NN] = s[63];
}

__global__ void scan_add(const int* __restrict__ excl, const int* __restrict__ blockoffs,
                         int* __restrict__ row_start, int* __restrict__ cursor)
{
    int i = blockIdx.x * 256 + threadIdx.x;
    if (i >= NN) return;
    int v = excl[i] + blockoffs[i >> 10];
    row_start[i] = v;
    cursor[i] = v;
}

__global__ void scatter_csr(const int* __restrict__ ei, int* __restrict__ cursor,
                            int* __restrict__ csr_src) {
    int e = blockIdx.x * 256 + threadIdx.x;
    if (e >= EPE) return;
    int s, d;
    if (e < EE) { s = ei[e]; d = ei[EE + e]; } else { s = d = e - EE; }
    int pos = atomicAdd(&cursor[d], 1);
    csr_src[pos] = s;
}

// ---------------- node GEMM (h -> bf16, skip -> fp32) ----------------
__global__ __launch_bounds__(256) void gemm_node(
    const float* __restrict__ X, const float* __restrict__ W, const float* __restrict__ SKW,
    const float* __restrict__ skb, const float* __restrict__ bb,
    ushort* __restrict__ Hout, float* __restrict__ Agg)
{
    __shared__ float Xs[128][68];   // [k][m]
    __shared__ float Ws[128][68];   // [k][c]
    const int row0 = blockIdx.x * 64;
    const int bc = blockIdx.y;                 // 0..3
    const int tid = threadIdx.x;
    const float* M = (bc < 2) ? W : SKW;
    const int colOff = (bc & 1) * 64;

    {
        int m = tid >> 2;
        int kq = (tid & 3) * 4;
        int n = row0 + m;
        #pragma unroll
        for (int it = 0; it < 8; ++it) {
            int k = kq + it * 16;
            float4 v = make_float4(0.f, 0.f, 0.f, 0.f);
            if (n < NN) v = *reinterpret_cast<const float4*>(X + (size_t)n * 128 + k);
            Xs[k + 0][m] = v.x; Xs[k + 1][m] = v.y; Xs[k + 2][m] = v.z; Xs[k + 3][m] = v.w;
        }
    }
    {
        int kr = tid >> 4;
        int c4 = (tid & 15) * 4;
        #pragma unroll
        for (int it = 0; it < 8; ++it) {
            int k = it * 16 + kr;
            float4 v = *reinterpret_cast<const float4*>(M + (size_t)k * 128 + colOff + c4);
            *reinterpret_cast<float4*>(&Ws[k][c4]) = v;
        }
    }
    __syncthreads();

    const int tx = tid & 15, ty = tid >> 4;
    float acc[4][4] = {};
    #pragma unroll 4
    for (int k = 0; k < 128; ++k) {
        float4 a = *reinterpret_cast<const float4*>(&Xs[k][ty * 4]);
        float4 b = *reinterpret_cast<const float4*>(&Ws[k][tx * 4]);
        float av[4] = {a.x, a.y, a.z, a.w};
        float bv[4] = {b.x, b.y, b.z, b.w};
        #pragma unroll
        for (int i = 0; i < 4; ++i) {
            #pragma unroll
            for (int j = 0; j < 4; ++j) acc[i][j] += av[i] * bv[j];
        }
    }

    #pragma unroll
    for (int i = 0; i < 4; ++i) {
        int n = row0 + ty * 4 + i;
        if (n >= NN) continue;
        int c = colOff + tx * 4;
        if (bc < 2) {
            ushort4 v;
            v.x = f2bf(acc[i][0]); v.y = f2bf(acc[i][1]);
            v.z = f2bf(acc[i][2]); v.w = f2bf(acc[i][3]);
            *reinterpret_cast<ushort4*>(Hout + (size_t)n * 128 + c) = v;
        } else {
            float4 v;
            v.x = acc[i][0] + skb[c + 0] + bb[c + 0];
            v.y = acc[i][1] + skb[c + 1] + bb[c + 1];
            v.z = acc[i][2] + skb[c + 2] + bb[c + 2];
            v.w = acc[i][3] + skb[c + 3] + bb[c + 3];
            *reinterpret_cast<float4*>(Agg + (size_t)n * 128 + c) = v;
        }
    }
}

// per-node attention coefficients e_src/e_dst [N,4] (bf16 h input)
__global__ __launch_bounds__(256) void node_attn(
    const ushort* __restrict__ Hb, const float* __restrict__ as_, const float* __restrict__ ad_,
    float* __restrict__ esrc, float* __restrict__ edst)
{
    int tid = threadIdx.x;
    int node = blockIdx.x * 2 + (tid >> 7);
    int t = tid & 127;
    if (node >= NN) return;
    float hv = bf2f(Hb[(size_t)node * 128 + t]);
    float p1 = hv * as_[t];
    float p2 = hv * ad_[t];
    #pragma unroll
    for (int o = 16; o > 0; o >>= 1) {
        p1 += __shfl_down(p1, o, 32);
        p2 += __shfl_down(p2, o, 32);
    }
    if ((t & 31) == 0) {
        esrc[node * 4 + (t >> 5)] = p1;
        edst[node * 4 + (t >> 5)] = p2;
    }
}

// ---------------- fused per-dst softmax + aggregate + skip + relu ----------------
// wave-parallel per-head online softmax: head group = 32 lanes (t>>5), (m,z) kept
// redundantly in registers across the group; shuffle-tree reductions.
__global__ __launch_bounds__(128) void gat_aggr(
    const int* __restrict__ row_start, const int* __restrict__ csr_src,
    const float* __restrict__ esrc, const float* __restrict__ edst,
    const ushort* __restrict__ Hb, const float* __restrict__ skipagg,
    float* __restrict__ outbuf)
{
    __shared__ int   lsrc[CHUNK];
    __shared__ float lw[CHUNK * 4];
    const int d = blockIdx.x;
    const int t = threadIdx.x;
    const int hd = t >> 5;
    const int l = t & 31;
    const int r0 = row_start[d], r1 = row_start[d + 1];
    const float4 edv = *reinterpret_cast<const float4*>(edst + (size_t)d * 4);
    float acc = 0.f;
    float m_h = -INFINITY, z_h = 0.f;

    for (int base = r0; base < r1; base += CHUNK) {
        const int nc = min(CHUNK, r1 - base);
        __syncthreads();   // protect lsrc/lw reuse vs previous chunk's accumulate
        for (int i = t; i < nc; i += 128) {
            int s = csr_src[base + i];
            lsrc[i] = s;
            float4 ev = *reinterpret_cast<const float4*>(esrc + (size_t)s * 4);
            lw[i * 4 + 0] = lrelu(ev.x + edv.x);
            lw[i * 4 + 1] = lrelu(ev.y + edv.y);
            lw[i * 4 + 2] = lrelu(ev.z + edv.z);
            lw[i * 4 + 3] = lrelu(ev.w + edv.w);
        }
        __syncthreads();
        // chunk max for this head (all 32 lanes participate, then tree-reduce)
        float mx = m_h;
        for (int i = l; i < nc; i += 32) mx = fmaxf(mx, lw[i * 4 + hd]);
        #pragma unroll
        for (int off = 16; off > 0; off >>= 1) mx = fmaxf(mx, __shfl_xor(mx, off, 32));
        float sc = __expf(m_h - mx);       // 0 on first chunk
        float zp = 0.f;
        for (int i = l; i < nc; i += 32) {
            float w = __expf(lw[i * 4 + hd] - mx);
            lw[i * 4 + hd] = w;
            zp += w;
        }
        #pragma unroll
        for (int off = 16; off > 0; off >>= 1) zp += __shfl_xor(zp, off, 32);
        z_h = z_h * sc + zp;
        m_h = mx;
        acc *= sc;
        __syncthreads();
        // weighted accumulation of h[src] rows (channel t, head hd)
        #pragma unroll 4
        for (int i = 0; i < nc; ++i) {
            acc += lw[i * 4 + hd] * bf2f(Hb[(size_t)lsrc[i] * 128 + t]);
        }
    }
    float res = skipagg[(size_t)d * 128 + t] + acc / z_h;
    outbuf[(size_t)d * 128 + t] = fmaxf(res, 0.f);
}

// ---------------- pooling + MLP ----------------
__global__ void pool_init(float* __restrict__ pooled) {
    int i = blockIdx.x * 256 + threadIdx.x;
    if (i < GGR * HCC) pooled[i] = -INFINITY;
}

__global__ void pool_max(const float* __restrict__ xf, const int* __restrict__ batch,
                         float* __restrict__ pooled)
{
    int i = blockIdx.x * 256 + threadIdx.x;
    if (i >= NN * HCC) return;
    int n = i >> 7, c = i & 127;
    atomicMaxF(&pooled[batch[n] * 128 + c], xf[i]);
}

__global__ __launch_bounds__(512) void mlp1(const float* __restrict__ pooled,
                                            const float* __restrict__ w,
                                            const float* __restrict__ bias,
                                            float* __restrict__ hid)
{
    __shared__ float xs[128];
    int g = blockIdx.x, t = threadIdx.x;
    if (t < 128) {
        float v = pooled[g * 128 + t];
        if (!isfinite(v)) v = 0.f;
        xs[t] = v;
    }
    __syncthreads();
    float acc = 0.f;
    #pragma unroll 8
    for (int k = 0; k < 128; ++k) acc += xs[k] * w[(size_t)k * NHIDD + t];
    hid[(size_t)g * NHIDD + t] = fmaxf(acc + bias[t], 0.f);
}

__global__ __launch_bounds__(768) void mlp2(const float* __restrict__ hid,
                                            const float* __restrict__ w,
                                            const float* __restrict__ bias,
                                            float* __restrict__ out)
{
    __shared__ float xs[NHIDD];
    int g = blockIdx.x, t = threadIdx.x;
    if (t < NHIDD) xs[t] = hid[(size_t)g * NHIDD + t];
    __syncthreads();
    float acc = 0.f;
    #pragma unroll 8
    for (int k = 0; k < NHIDD; ++k) acc += xs[k] * w[(size_t)k * NOUTD + t];
    out[(size_t)g * NOUTD + t] = acc + bias[t];
}

extern "C" void kernel_launch(void* const* d_in, const int* in_sizes, int n_in,
                              void* d_out, int out_size, void* d_ws, size_t ws_size,
                              hipStream_t stream)
{
    const float* x = (const float*)d_in[0];
    const int* ei = (const int*)d_in[1];
    const int* batch = (const int*)d_in[2];
    const float* W[3]   = {(const float*)d_in[3],  (const float*)d_in[9],  (const float*)d_in[15]};
    const float* AS[3]  = {(const float*)d_in[4],  (const float*)d_in[10], (const float*)d_in[16]};
    const float* AD[3]  = {(const float*)d_in[5],  (const float*)d_in[11], (const float*)d_in[17]};
    const float* B[3]   = {(const float*)d_in[6],  (const float*)d_in[12], (const float*)d_in[18]};
    const float* SKW[3] = {(const float*)d_in[7],  (const float*)d_in[13], (const float*)d_in[19]};
    const float* SKB[3] = {(const float*)d_in[8],  (const float*)d_in[14], (const float*)d_in[20]};
    const float* m1w = (const float*)d_in[21];
    const float* m1b = (const float*)d_in[22];
    const float* m2w = (const float*)d_in[23];
    const float* m2b = (const float*)d_in[24];
    float* out = (float*)d_out;

    float* p = (float*)d_ws;
    float* bufA = p; p += (size_t)NN * HCC;
    float* bufB = p; p += (size_t)NN * HCC;
    ushort* hbuf = (ushort*)p; p += (size_t)NN * HCC / 2;
    float* agg  = p; p += (size_t)NN * HCC;
    float* esrc = p; p += NN * 4;
    float* edst = p; p += NN * 4;
    float* pooled = p; p += GGR * HCC;
    float* hidden = p; p += GGR * NHIDD;
    int* counts    = (int*)p; p += NN;
    int* excl      = (int*)p; p += NN;
    int* row_start = (int*)p; p += NN + 4;
    int* cursor    = (int*)p; p += NN;
    int* csr_src   = (int*)p; p += EPE;
    int* blocksums = (int*)p; p += 64;
    int* blockoffs = (int*)p; p += 64;

    // CSR build (dst-sorted edges), once per call
    hist_zero<<<(NN + 255) / 256, 256, 0, stream>>>(counts);
    hist<<<(EPE + 255) / 256, 256, 0, stream>>>(ei, counts);
    scan_partial<<<SCAN_NBLK, 256, 0, stream>>>(counts, excl, blocksums);
    scan_sums<<<1, 64, 0, stream>>>(blocksums, blockoffs, row_start);
    scan_add<<<(NN + 255) / 256, 256, 0, stream>>>(excl, blockoffs, row_start, cursor);
    scatter_csr<<<(EPE + 255) / 256, 256, 0, stream>>>(ei, cursor, csr_src);

    const float* cur = x;
    float* outs[3] = {bufA, bufB, bufA};
    for (int l = 0; l < 3; ++l) {
        dim3 gg((NN + 63) / 64, 4);
        gemm_node<<<gg, 256, 0, stream>>>(cur, W[l], SKW[l], SKB[l], B[l], hbuf, agg);
        node_attn<<<NN / 2, 256, 0, stream>>>(hbuf, AS[l], AD[l], esrc, edst);
        gat_aggr<<<NN, 128, 0, stream>>>(row_start, csr_src, esrc, edst, hbuf, agg, outs[l]);
        cur = outs[l];
    }
    pool_init<<<(GGR * HCC) / 256, 256, 0, stream>>>(pooled);
    pool_max<<<(NN * HCC + 255) / 256, 256, 0, stream>>>(cur, batch, pooled);
    mlp1<<<GGR, NHIDD, 0, stream>>>(pooled, m1w, m1b, hidden);
    mlp2<<<GGR, NOUTD, 0, stream>>>(hidden, m2w, m2b, out);
}

// Round 6
// 582.452 us; speedup vs baseline: 4.1330x; 1.1266x over previous
//
#include <hip/hip_runtime.h>
#include <hip/hip_bf16.h>
#include <math.h>

#define NN 50000
#define EE 800000
#define EPE 850000   // EE + NN self loops
#define HCC 128
#define GGR 256
#define NHIDD 512
#define NOUTD 768
#define CHUNK 256
#define SCAN_NBLK ((NN + 1023) / 1024)   // 49
#define MBLK ((NN + 63) / 64)            // 782

typedef __attribute__((ext_vector_type(8))) short bf16x8;
typedef __attribute__((ext_vector_type(4))) float f32x4;

__device__ __forceinline__ void atomicMaxF(float* addr, float v) {
    if (v >= 0.f) atomicMax(reinterpret_cast<int*>(addr), __float_as_int(v));
    else atomicMin(reinterpret_cast<unsigned int*>(addr), __float_as_uint(v));
}

__device__ __forceinline__ float lrelu(float x) { return x > 0.f ? x : 0.2f * x; }

__device__ __forceinline__ ushort f2bf(float f) {
    unsigned u = __float_as_uint(f);
    unsigned r = (u + 0x7fffu + ((u >> 16) & 1u)) >> 16;   // RNE
    return (ushort)r;
}
__device__ __forceinline__ float bf2f(ushort b) {
    return __uint_as_float(((unsigned)b) << 16);
}

// ---------------- converts ----------------
__global__ void conv_x(const float* __restrict__ X, ushort* __restrict__ Xb) {
    int i = blockIdx.x * 256 + threadIdx.x;
    if (i < NN * HCC / 4) {
        float4 v = reinterpret_cast<const float4*>(X)[i];
        ushort4 o;
        o.x = f2bf(v.x); o.y = f2bf(v.y); o.z = f2bf(v.z); o.w = f2bf(v.w);
        reinterpret_cast<ushort4*>(Xb)[i] = o;
    }
}

// Wt[n][k] = bf16( n<128 ? W[k][n] : SKW[k][n-128] ),  [256][128]
__global__ void conv_w(const float* __restrict__ W, const float* __restrict__ SKW,
                       ushort* __restrict__ Wt) {
    int i = blockIdx.x * 256 + threadIdx.x;
    if (i >= 256 * 128) return;
    int n = i >> 7, k = i & 127;
    float v = (n < 128) ? W[(size_t)k * 128 + n] : SKW[(size_t)k * 128 + (n - 128)];
    Wt[i] = f2bf(v);
}

// ---------------- CSR build (once per call) ----------------
__global__ void hist_zero(int* __restrict__ counts) {
    int i = blockIdx.x * 256 + threadIdx.x;
    if (i < NN) counts[i] = 0;
}

__global__ void hist(const int* __restrict__ ei, int* __restrict__ counts) {
    int e = blockIdx.x * 256 + threadIdx.x;
    if (e >= EPE) return;
    int d = (e < EE) ? ei[EE + e] : e - EE;
    atomicAdd(&counts[d], 1);
}

__global__ __launch_bounds__(256) void scan_partial(const int* __restrict__ counts,
                                                    int* __restrict__ excl,
                                                    int* __restrict__ blocksums)
{
    __shared__ int s[256];
    const int b = blockIdx.x, t = threadIdx.x;
    const int idx = b * 1024 + t * 4;
    int a0 = (idx + 0 < NN) ? counts[idx + 0] : 0;
    int a1 = (idx + 1 < NN) ? counts[idx + 1] : 0;
    int a2 = (idx + 2 < NN) ? counts[idx + 2] : 0;
    int a3 = (idx + 3 < NN) ? counts[idx + 3] : 0;
    int sum4 = a0 + a1 + a2 + a3;
    s[t] = sum4;
    __syncthreads();
    #pragma unroll
    for (int off = 1; off < 256; off <<= 1) {
        int add = (t >= off) ? s[t - off] : 0;
        __syncthreads();
        s[t] += add;
        __syncthreads();
    }
    int e0 = s[t] - sum4;
    if (idx + 0 < NN) excl[idx + 0] = e0;
    if (idx + 1 < NN) excl[idx + 1] = e0 + a0;
    if (idx + 2 < NN) excl[idx + 2] = e0 + a0 + a1;
    if (idx + 3 < NN) excl[idx + 3] = e0 + a0 + a1 + a2;
    if (t == 255) blocksums[b] = s[255];
}

__global__ __launch_bounds__(64) void scan_sums(int* __restrict__ blocksums,
                                                int* __restrict__ blockoffs,
                                                int* __restrict__ row_start)
{
    __shared__ int s[64];
    int t = threadIdx.x;
    int v = (t < SCAN_NBLK) ? blocksums[t] : 0;
    s[t] = v;
    __syncthreads();
    #pragma unroll
    for (int off = 1; off < 64; off <<= 1) {
        int add = (t >= off) ? s[t - off] : 0;
        __syncthreads();
        s[t] += add;
        __syncthreads();
    }
    if (t < SCAN_NBLK) blockoffs[t] = s[t] - v;
    if (t == 63) row_start[NN] = s[63];
}

__global__ void scan_add(const int* __restrict__ excl, const int* __restrict__ blockoffs,
                         int* __restrict__ row_start, int* __restrict__ cursor)
{
    int i = blockIdx.x * 256 + threadIdx.x;
    if (i >= NN) return;
    int v = excl[i] + blockoffs[i >> 10];
    row_start[i] = v;
    cursor[i] = v;
}

__global__ void scatter_csr(const int* __restrict__ ei, int* __restrict__ cursor,
                            int* __restrict__ csr_src) {
    int e = blockIdx.x * 256 + threadIdx.x;
    if (e >= EPE) return;
    int s, d;
    if (e < EE) { s = ei[e]; d = ei[EE + e]; } else { s = d = e - EE; }
    int pos = atomicAdd(&cursor[d], 1);
    csr_src[pos] = s;
}

// ---------------- MFMA node GEMM: [64 rows] x [256 cols], K=128 ----------------
// cols 0-127 -> h (bf16), cols 128-255 -> skip + skb + b (fp32)
__global__ __launch_bounds__(256) void gemm_mfma(
    const ushort* __restrict__ Xb,   // [NN][128] bf16
    const ushort* __restrict__ Wt,   // [256][128] bf16, row n holds column n of W||SKW
    const float* __restrict__ skb, const float* __restrict__ bb,
    ushort* __restrict__ Hout, float* __restrict__ Agg)
{
    __shared__ ushort Xs[64 * 128];          // 16 KB, XOR-swizzled rows
    const int r0 = blockIdx.x * 64;
    const int tid = threadIdx.x;
    const int w = tid >> 6;                  // wave 0..3
    const int l = tid & 63;
    const int lm = l & 15;                   // A-row / B-col / D-col lane index
    const int lk = l >> 4;                   // k-group

    // stage X tile: 64 rows x 256 B; swizzle byte col ^= (row&7)<<4
    #pragma unroll
    for (int it = 0; it < 4; ++it) {
        int slot = it * 256 + tid;           // 16B slots, 16 per row
        int row = slot >> 4;
        int bc = (slot & 15) << 4;           // byte col
        int n = r0 + row;
        bf16x8 v = (bf16x8)(short)0;
        if (n < NN) v = *reinterpret_cast<const bf16x8*>(Xb + (size_t)n * 128 + (bc >> 1));
        *reinterpret_cast<bf16x8*>(reinterpret_cast<char*>(Xs) + row * 256 + (bc ^ ((row & 7) << 4))) = v;
    }
    __syncthreads();

    f32x4 acc[4][4];                         // [col-slab nb][row-frag rf]
    #pragma unroll
    for (int nb = 0; nb < 4; ++nb)
        #pragma unroll
        for (int rf = 0; rf < 4; ++rf)
            acc[nb][rf] = (f32x4){0.f, 0.f, 0.f, 0.f};

    #pragma unroll
    for (int ks = 0; ks < 4; ++ks) {
        bf16x8 a[4];
        #pragma unroll
        for (int rf = 0; rf < 4; ++rf) {
            int row = rf * 16 + lm;
            int bc = (ks * 32 + lk * 8) * 2;
            a[rf] = *reinterpret_cast<const bf16x8*>(
                reinterpret_cast<const char*>(Xs) + row * 256 + (bc ^ ((row & 7) << 4)));
        }
        #pragma unroll
        for (int nb = 0; nb < 4; ++nb) {
            int ncol = (w * 4 + nb) * 16 + lm;
            bf16x8 b = *reinterpret_cast<const bf16x8*>(Wt + (size_t)ncol * 128 + ks * 32 + lk * 8);
            #pragma unroll
            for (int rf = 0; rf < 4; ++rf)
                acc[nb][rf] = __builtin_amdgcn_mfma_f32_16x16x32_bf16(a[rf], b, acc[nb][rf], 0, 0, 0);
        }
    }

    // epilogue: D[row=(l>>4)*4+r][col=l&15] per frag
    #pragma unroll
    for (int nb = 0; nb < 4; ++nb) {
        int ncol = (w * 4 + nb) * 16 + lm;
        #pragma unroll
        for (int rf = 0; rf < 4; ++rf) {
            #pragma unroll
            for (int r = 0; r < 4; ++r) {
                int n = r0 + rf * 16 + lk * 4 + r;
                if (n >= NN) continue;
                float v = acc[nb][rf][r];
                if (ncol < 128) {
                    Hout[(size_t)n * 128 + ncol] = f2bf(v);
                } else {
                    int c = ncol - 128;
                    Agg[(size_t)n * 128 + c] = v + skb[c] + bb[c];
                }
            }
        }
    }
}

// per-node attention coefficients e_src/e_dst [N,4] (bf16 h input)
__global__ __launch_bounds__(256) void node_attn(
    const ushort* __restrict__ Hb, const float* __restrict__ as_, const float* __restrict__ ad_,
    float* __restrict__ esrc, float* __restrict__ edst)
{
    int tid = threadIdx.x;
    int node = blockIdx.x * 2 + (tid >> 7);
    int t = tid & 127;
    if (node >= NN) return;
    float hv = bf2f(Hb[(size_t)node * 128 + t]);
    float p1 = hv * as_[t];
    float p2 = hv * ad_[t];
    #pragma unroll
    for (int o = 16; o > 0; o >>= 1) {
        p1 += __shfl_down(p1, o, 32);
        p2 += __shfl_down(p2, o, 32);
    }
    if ((t & 31) == 0) {
        esrc[node * 4 + (t >> 5)] = p1;
        edst[node * 4 + (t >> 5)] = p2;
    }
}

// ---------------- fused per-dst softmax + aggregate + skip + relu (bf16 out) ----------------
__global__ __launch_bounds__(128) void gat_aggr(
    const int* __restrict__ row_start, const int* __restrict__ csr_src,
    const float* __restrict__ esrc, const float* __restrict__ edst,
    const ushort* __restrict__ Hb, const float* __restrict__ skipagg,
    ushort* __restrict__ outbuf)
{
    __shared__ int   lsrc[CHUNK];
    __shared__ float lw[CHUNK * 4];
    const int d = blockIdx.x;
    const int t = threadIdx.x;
    const int hd = t >> 5;
    const int l = t & 31;
    const int r0 = row_start[d], r1 = row_start[d + 1];
    const float4 edv = *reinterpret_cast<const float4*>(edst + (size_t)d * 4);
    float acc = 0.f;
    float m_h = -INFINITY, z_h = 0.f;

    for (int base = r0; base < r1; base += CHUNK) {
        const int nc = min(CHUNK, r1 - base);
        __syncthreads();
        for (int i = t; i < nc; i += 128) {
            int s = csr_src[base + i];
            lsrc[i] = s;
            float4 ev = *reinterpret_cast<const float4*>(esrc + (size_t)s * 4);
            lw[i * 4 + 0] = lrelu(ev.x + edv.x);
            lw[i * 4 + 1] = lrelu(ev.y + edv.y);
            lw[i * 4 + 2] = lrelu(ev.z + edv.z);
            lw[i * 4 + 3] = lrelu(ev.w + edv.w);
        }
        __syncthreads();
        float mx = m_h;
        for (int i = l; i < nc; i += 32) mx = fmaxf(mx, lw[i * 4 + hd]);
        #pragma unroll
        for (int off = 16; off > 0; off >>= 1) mx = fmaxf(mx, __shfl_xor(mx, off, 32));
        float sc = __expf(m_h - mx);
        float zp = 0.f;
        for (int i = l; i < nc; i += 32) {
            float w = __expf(lw[i * 4 + hd] - mx);
            lw[i * 4 + hd] = w;
            zp += w;
        }
        #pragma unroll
        for (int off = 16; off > 0; off >>= 1) zp += __shfl_xor(zp, off, 32);
        z_h = z_h * sc + zp;
        m_h = mx;
        acc *= sc;
        __syncthreads();
        #pragma unroll 4
        for (int i = 0; i < nc; ++i) {
            acc += lw[i * 4 + hd] * bf2f(Hb[(size_t)lsrc[i] * 128 + t]);
        }
    }
    float res = skipagg[(size_t)d * 128 + t] + acc / z_h;
    outbuf[(size_t)d * 128 + t] = f2bf(fmaxf(res, 0.f));
}

// ---------------- pooling + MLP ----------------
__global__ void pool_init(float* __restrict__ pooled) {
    int i = blockIdx.x * 256 + threadIdx.x;
    if (i < GGR * HCC) pooled[i] = -INFINITY;
}

__global__ void pool_max(const ushort* __restrict__ xf, const int* __restrict__ batch,
                         float* __restrict__ pooled)
{
    int i = blockIdx.x * 256 + threadIdx.x;
    if (i >= NN * HCC) return;
    int n = i >> 7, c = i & 127;
    atomicMaxF(&pooled[batch[n] * 128 + c], bf2f(xf[i]));
}

__global__ __launch_bounds__(512) void mlp1(const float* __restrict__ pooled,
                                            const float* __restrict__ w,
                                            const float* __restrict__ bias,
                                            float* __restrict__ hid)
{
    __shared__ float xs[128];
    int g = blockIdx.x, t = threadIdx.x;
    if (t < 128) {
        float v = pooled[g * 128 + t];
        if (!isfinite(v)) v = 0.f;
        xs[t] = v;
    }
    __syncthreads();
    float acc = 0.f;
    #pragma unroll 8
    for (int k = 0; k < 128; ++k) acc += xs[k] * w[(size_t)k * NHIDD + t];
    hid[(size_t)g * NHIDD + t] = fmaxf(acc + bias[t], 0.f);
}

__global__ __launch_bounds__(768) void mlp2(const float* __restrict__ hid,
                                            const float* __restrict__ w,
                                            const float* __restrict__ bias,
                                            float* __restrict__ out)
{
    __shared__ float xs[NHIDD];
    int g = blockIdx.x, t = threadIdx.x;
    if (t < NHIDD) xs[t] = hid[(size_t)g * NHIDD + t];
    __syncthreads();
    float acc = 0.f;
    #pragma unroll 8
    for (int k = 0; k < NHIDD; ++k) acc += xs[k] * w[(size_t)k * NOUTD + t];
    out[(size_t)g * NOUTD + t] = acc + bias[t];
}

extern "C" void kernel_launch(void* const* d_in, const int* in_sizes, int n_in,
                              void* d_out, int out_size, void* d_ws, size_t ws_size,
                              hipStream_t stream)
{
    const float* x = (const float*)d_in[0];
    const int* ei = (const int*)d_in[1];
    const int* batch = (const int*)d_in[2];
    const float* W[3]   = {(const float*)d_in[3],  (const float*)d_in[9],  (const float*)d_in[15]};
    const float* AS[3]  = {(const float*)d_in[4],  (const float*)d_in[10], (const float*)d_in[16]};
    const float* AD[3]  = {(const float*)d_in[5],  (const float*)d_in[11], (const float*)d_in[17]};
    const float* B[3]   = {(const float*)d_in[6],  (const float*)d_in[12], (const float*)d_in[18]};
    const float* SKW[3] = {(const float*)d_in[7],  (const float*)d_in[13], (const float*)d_in[19]};
    const float* SKB[3] = {(const float*)d_in[8],  (const float*)d_in[14], (const float*)d_in[20]};
    const float* m1w = (const float*)d_in[21];
    const float* m1b = (const float*)d_in[22];
    const float* m2w = (const float*)d_in[23];
    const float* m2b = (const float*)d_in[24];
    float* out = (float*)d_out;

    float* p = (float*)d_ws;
    ushort* bufA = (ushort*)p; p += (size_t)NN * HCC / 2;
    ushort* bufB = (ushort*)p; p += (size_t)NN * HCC / 2;
    ushort* xb   = (ushort*)p; p += (size_t)NN * HCC / 2;
    ushort* hbuf = (ushort*)p; p += (size_t)NN * HCC / 2;
    ushort* wt3  = (ushort*)p; p += 3 * 256 * 128 / 2;
    float* agg  = p; p += (size_t)NN * HCC;
    float* esrc = p; p += NN * 4;
    float* edst = p; p += NN * 4;
    float* pooled = p; p += GGR * HCC;
    float* hidden = p; p += GGR * NHIDD;
    int* counts    = (int*)p; p += NN;
    int* excl      = (int*)p; p += NN;
    int* row_start = (int*)p; p += NN + 4;
    int* cursor    = (int*)p; p += NN;
    int* csr_src   = (int*)p; p += EPE;
    int* blocksums = (int*)p; p += 64;
    int* blockoffs = (int*)p; p += 64;

    // converts
    conv_x<<<(NN * HCC / 4 + 255) / 256, 256, 0, stream>>>(x, xb);
    for (int l = 0; l < 3; ++l)
        conv_w<<<(256 * 128 + 255) / 256, 256, 0, stream>>>(W[l], SKW[l], wt3 + l * 256 * 128);

    // CSR build (dst-sorted edges), once per call
    hist_zero<<<(NN + 255) / 256, 256, 0, stream>>>(counts);
    hist<<<(EPE + 255) / 256, 256, 0, stream>>>(ei, counts);
    scan_partial<<<SCAN_NBLK, 256, 0, stream>>>(counts, excl, blocksums);
    scan_sums<<<1, 64, 0, stream>>>(blocksums, blockoffs, row_start);
    scan_add<<<(NN + 255) / 256, 256, 0, stream>>>(excl, blockoffs, row_start, cursor);
    scatter_csr<<<(EPE + 255) / 256, 256, 0, stream>>>(ei, cursor, csr_src);

    const ushort* cur = xb;
    ushort* outs[3] = {bufA, bufB, bufA};
    for (int l = 0; l < 3; ++l) {
        gemm_mfma<<<MBLK, 256, 0, stream>>>(cur, wt3 + l * 256 * 128, SKB[l], B[l], hbuf, agg);
        node_attn<<<NN / 2, 256, 0, stream>>>(hbuf, AS[l], AD[l], esrc, edst);
        gat_aggr<<<NN, 128, 0, stream>>>(row_start, csr_src, esrc, edst, hbuf, agg, outs[l]);
        cur = outs[l];
    }
    pool_init<<<(GGR * HCC) / 256, 256, 0, stream>>>(pooled);
    pool_max<<<(NN * HCC + 255) / 256, 256, 0, stream>>>(cur, batch, pooled);
    mlp1<<<GGR, NHIDD, 0, stream>>>(pooled, m1w, m1b, hidden);
    mlp2<<<GGR, NOUTD, 0, stream>>>(hidden, m2w, m2b, out);
}

// Round 7
// 545.349 us; speedup vs baseline: 4.4142x; 1.0680x over previous
//
#include <hip/hip_runtime.h>
#include <hip/hip_bf16.h>
#include <math.h>

#define NN 50000
#define EE 800000
#define EPE 850000   // EE + NN self loops
#define HCC 128
#define GGR 256
#define NHIDD 512
#define NOUTD 768
#define CHUNK 256
#define CPAD (CHUNK + 8)
#define SCAN_NBLK ((NN + 1023) / 1024)   // 49
#define MBLK ((NN + 63) / 64)            // 782

typedef __attribute__((ext_vector_type(8))) short bf16x8;
typedef __attribute__((ext_vector_type(4))) float f32x4;

__device__ __forceinline__ void atomicMaxF(float* addr, float v) {
    if (v >= 0.f) atomicMax(reinterpret_cast<int*>(addr), __float_as_int(v));
    else atomicMin(reinterpret_cast<unsigned int*>(addr), __float_as_uint(v));
}

__device__ __forceinline__ float lrelu(float x) { return x > 0.f ? x : 0.2f * x; }

__device__ __forceinline__ ushort f2bf(float f) {
    unsigned u = __float_as_uint(f);
    unsigned r = (u + 0x7fffu + ((u >> 16) & 1u)) >> 16;   // RNE
    return (ushort)r;
}
__device__ __forceinline__ float bf2f(ushort b) {
    return __uint_as_float(((unsigned)b) << 16);
}

// ---------------- converts ----------------
__global__ void conv_x(const float* __restrict__ X, ushort* __restrict__ Xb) {
    int i = blockIdx.x * 256 + threadIdx.x;
    if (i < NN * HCC / 4) {
        float4 v = reinterpret_cast<const float4*>(X)[i];
        ushort4 o;
        o.x = f2bf(v.x); o.y = f2bf(v.y); o.z = f2bf(v.z); o.w = f2bf(v.w);
        reinterpret_cast<ushort4*>(Xb)[i] = o;
    }
}

// Wt[n][k] = bf16( n<128 ? W[k][n] : SKW[k][n-128] ),  [256][128]
__global__ void conv_w(const float* __restrict__ W, const float* __restrict__ SKW,
                       ushort* __restrict__ Wt) {
    int i = blockIdx.x * 256 + threadIdx.x;
    if (i >= 256 * 128) return;
    int n = i >> 7, k = i & 127;
    float v = (n < 128) ? W[(size_t)k * 128 + n] : SKW[(size_t)k * 128 + (n - 128)];
    Wt[i] = f2bf(v);
}

// ---------------- CSR build (once per call) ----------------
__global__ void hist_zero(int* __restrict__ counts) {
    int i = blockIdx.x * 256 + threadIdx.x;
    if (i < NN) counts[i] = 0;
}

__global__ void hist(const int* __restrict__ ei, int* __restrict__ counts) {
    int e = blockIdx.x * 256 + threadIdx.x;
    if (e >= EPE) return;
    int d = (e < EE) ? ei[EE + e] : e - EE;
    atomicAdd(&counts[d], 1);
}

__global__ __launch_bounds__(256) void scan_partial(const int* __restrict__ counts,
                                                    int* __restrict__ excl,
                                                    int* __restrict__ blocksums)
{
    __shared__ int s[256];
    const int b = blockIdx.x, t = threadIdx.x;
    const int idx = b * 1024 + t * 4;
    int a0 = (idx + 0 < NN) ? counts[idx + 0] : 0;
    int a1 = (idx + 1 < NN) ? counts[idx + 1] : 0;
    int a2 = (idx + 2 < NN) ? counts[idx + 2] : 0;
    int a3 = (idx + 3 < NN) ? counts[idx + 3] : 0;
    int sum4 = a0 + a1 + a2 + a3;
    s[t] = sum4;
    __syncthreads();
    #pragma unroll
    for (int off = 1; off < 256; off <<= 1) {
        int add = (t >= off) ? s[t - off] : 0;
        __syncthreads();
        s[t] += add;
        __syncthreads();
    }
    int e0 = s[t] - sum4;
    if (idx + 0 < NN) excl[idx + 0] = e0;
    if (idx + 1 < NN) excl[idx + 1] = e0 + a0;
    if (idx + 2 < NN) excl[idx + 2] = e0 + a0 + a1;
    if (idx + 3 < NN) excl[idx + 3] = e0 + a0 + a1 + a2;
    if (t == 255) blocksums[b] = s[255];
}

__global__ __launch_bounds__(64) void scan_sums(int* __restrict__ blocksums,
                                                int* __restrict__ blockoffs,
                                                int* __restrict__ row_start)
{
    __shared__ int s[64];
    int t = threadIdx.x;
    int v = (t < SCAN_NBLK) ? blocksums[t] : 0;
    s[t] = v;
    __syncthreads();
    #pragma unroll
    for (int off = 1; off < 64; off <<= 1) {
        int add = (t >= off) ? s[t - off] : 0;
        __syncthreads();
        s[t] += add;
        __syncthreads();
    }
    if (t < SCAN_NBLK) blockoffs[t] = s[t] - v;
    if (t == 63) row_start[NN] = s[63];
}

__global__ void scan_add(const int* __restrict__ excl, const int* __restrict__ blockoffs,
                         int* __restrict__ row_start, int* __restrict__ cursor)
{
    int i = blockIdx.x * 256 + threadIdx.x;
    if (i >= NN) return;
    int v = excl[i] + blockoffs[i >> 10];
    row_start[i] = v;
    cursor[i] = v;
}

__global__ void scatter_csr(const int* __restrict__ ei, int* __restrict__ cursor,
                            int* __restrict__ csr_src) {
    int e = blockIdx.x * 256 + threadIdx.x;
    if (e >= EPE) return;
    int s, d;
    if (e < EE) { s = ei[e]; d = ei[EE + e]; } else { s = d = e - EE; }
    int pos = atomicAdd(&cursor[d], 1);
    csr_src[pos] = s;
}

// ---------------- MFMA node GEMM: [64 rows] x [256 cols], K=128 ----------------
__global__ __launch_bounds__(256) void gemm_mfma(
    const ushort* __restrict__ Xb,   // [NN][128] bf16
    const ushort* __restrict__ Wt,   // [256][128] bf16
    const float* __restrict__ skb, const float* __restrict__ bb,
    ushort* __restrict__ Hout, float* __restrict__ Agg)
{
    __shared__ ushort Xs[64 * 128];          // 16 KB, XOR-swizzled rows
    const int r0 = blockIdx.x * 64;
    const int tid = threadIdx.x;
    const int w = tid >> 6;                  // wave 0..3
    const int l = tid & 63;
    const int lm = l & 15;
    const int lk = l >> 4;

    #pragma unroll
    for (int it = 0; it < 4; ++it) {
        int slot = it * 256 + tid;
        int row = slot >> 4;
        int bc = (slot & 15) << 4;
        int n = r0 + row;
        bf16x8 v = (bf16x8)(short)0;
        if (n < NN) v = *reinterpret_cast<const bf16x8*>(Xb + (size_t)n * 128 + (bc >> 1));
        *reinterpret_cast<bf16x8*>(reinterpret_cast<char*>(Xs) + row * 256 + (bc ^ ((row & 7) << 4))) = v;
    }
    __syncthreads();

    f32x4 acc[4][4];
    #pragma unroll
    for (int nb = 0; nb < 4; ++nb)
        #pragma unroll
        for (int rf = 0; rf < 4; ++rf)
            acc[nb][rf] = (f32x4){0.f, 0.f, 0.f, 0.f};

    #pragma unroll
    for (int ks = 0; ks < 4; ++ks) {
        bf16x8 a[4];
        #pragma unroll
        for (int rf = 0; rf < 4; ++rf) {
            int row = rf * 16 + lm;
            int bc = (ks * 32 + lk * 8) * 2;
            a[rf] = *reinterpret_cast<const bf16x8*>(
                reinterpret_cast<const char*>(Xs) + row * 256 + (bc ^ ((row & 7) << 4)));
        }
        #pragma unroll
        for (int nb = 0; nb < 4; ++nb) {
            int ncol = (w * 4 + nb) * 16 + lm;
            bf16x8 b = *reinterpret_cast<const bf16x8*>(Wt + (size_t)ncol * 128 + ks * 32 + lk * 8);
            #pragma unroll
            for (int rf = 0; rf < 4; ++rf)
                acc[nb][rf] = __builtin_amdgcn_mfma_f32_16x16x32_bf16(a[rf], b, acc[nb][rf], 0, 0, 0);
        }
    }

    #pragma unroll
    for (int nb = 0; nb < 4; ++nb) {
        int ncol = (w * 4 + nb) * 16 + lm;
        #pragma unroll
        for (int rf = 0; rf < 4; ++rf) {
            #pragma unroll
            for (int r = 0; r < 4; ++r) {
                int n = r0 + rf * 16 + lk * 4 + r;
                if (n >= NN) continue;
                float v = acc[nb][rf][r];
                if (ncol < 128) {
                    Hout[(size_t)n * 128 + ncol] = f2bf(v);
                } else {
                    int c = ncol - 128;
                    Agg[(size_t)n * 128 + c] = v + skb[c] + bb[c];
                }
            }
        }
    }
}

// per-node attention coefficients e_src/e_dst [N,4] (bf16 h input)
__global__ __launch_bounds__(256) void node_attn(
    const ushort* __restrict__ Hb, const float* __restrict__ as_, const float* __restrict__ ad_,
    float* __restrict__ esrc, float* __restrict__ edst)
{
    int tid = threadIdx.x;
    int node = blockIdx.x * 2 + (tid >> 7);
    int t = tid & 127;
    if (node >= NN) return;
    float hv = bf2f(Hb[(size_t)node * 128 + t]);
    float p1 = hv * as_[t];
    float p2 = hv * ad_[t];
    #pragma unroll
    for (int o = 16; o > 0; o >>= 1) {
        p1 += __shfl_down(p1, o, 32);
        p2 += __shfl_down(p2, o, 32);
    }
    if ((t & 31) == 0) {
        esrc[node * 4 + (t >> 5)] = p1;
        edst[node * 4 + (t >> 5)] = p2;
    }
}

// ---------------- fused per-dst softmax + aggregate + skip + relu ----------------
// softmax phase: head hd=t>>5, 32 lanes each, shuffle reductions (m,z in regs).
// gather phase: slot=t>>4 (edge lane), cg=t&15 (8 channels), wave covers 4 edges
// per iteration with one 16B load per lane; slot partials combined via LDS.
__global__ __launch_bounds__(128) void gat_aggr(
    const int* __restrict__ row_start, const int* __restrict__ csr_src,
    const float* __restrict__ esrc, const float* __restrict__ edst,
    const ushort* __restrict__ Hb, const float* __restrict__ skipagg,
    ushort* __restrict__ outbuf)
{
    __shared__ int   lsrc[CHUNK];
    __shared__ float lw[4][CPAD];
    __shared__ float shsc[4];
    __shared__ float accbuf[8][HCC];
    const int d = blockIdx.x;
    const int t = threadIdx.x;
    const int hd = t >> 5;
    const int l = t & 31;
    const int slot = t >> 4;       // 0..7
    const int cg = t & 15;
    const int c0 = cg * 8;
    const int ghd = cg >> 2;       // gather-phase head
    const int r0 = row_start[d], r1 = row_start[d + 1];
    const float4 edv = *reinterpret_cast<const float4*>(edst + (size_t)d * 4);
    float acc[8] = {0.f, 0.f, 0.f, 0.f, 0.f, 0.f, 0.f, 0.f};
    float m_h = -INFINITY, z_h = 0.f;

    for (int base = r0; base < r1; base += CHUNK) {
        const int nc = min(CHUNK, r1 - base);
        __syncthreads();
        for (int i = t; i < nc; i += 128) {
            int s = csr_src[base + i];
            lsrc[i] = s;
            float4 ev = *reinterpret_cast<const float4*>(esrc + (size_t)s * 4);
            lw[0][i] = lrelu(ev.x + edv.x);
            lw[1][i] = lrelu(ev.y + edv.y);
            lw[2][i] = lrelu(ev.z + edv.z);
            lw[3][i] = lrelu(ev.w + edv.w);
        }
        __syncthreads();
        float mx = m_h;
        for (int i = l; i < nc; i += 32) mx = fmaxf(mx, lw[hd][i]);
        #pragma unroll
        for (int off = 16; off > 0; off >>= 1) mx = fmaxf(mx, __shfl_xor(mx, off, 32));
        float sc = __expf(m_h - mx);
        float zp = 0.f;
        for (int i = l; i < nc; i += 32) {
            float w = __expf(lw[hd][i] - mx);
            lw[hd][i] = w;
            zp += w;
        }
        #pragma unroll
        for (int off = 16; off > 0; off >>= 1) zp += __shfl_xor(zp, off, 32);
        z_h = z_h * sc + zp;
        m_h = mx;
        if (l == 0) shsc[hd] = sc;
        __syncthreads();
        // gather: 8 edges per block-iteration, 16B loads
        float scg = shsc[ghd];
        #pragma unroll
        for (int j = 0; j < 8; ++j) acc[j] *= scg;
        for (int i = slot; i < nc; i += 8) {
            int s = lsrc[i];
            float wgt = lw[ghd][i];
            bf16x8 row = *reinterpret_cast<const bf16x8*>(Hb + (size_t)s * 128 + c0);
            #pragma unroll
            for (int j = 0; j < 8; ++j)
                acc[j] = fmaf(wgt, bf2f((ushort)row[j]), acc[j]);
        }
    }
    #pragma unroll
    for (int j = 0; j < 8; ++j) accbuf[slot][c0 + j] = acc[j];
    __syncthreads();
    float tot = 0.f;
    #pragma unroll
    for (int s = 0; s < 8; ++s) tot += accbuf[s][t];
    float res = skipagg[(size_t)d * 128 + t] + tot / z_h;
    outbuf[(size_t)d * 128 + t] = f2bf(fmaxf(res, 0.f));
}

// ---------------- pooling + MLP ----------------
__global__ void pool_init(float* __restrict__ pooled) {
    int i = blockIdx.x * 256 + threadIdx.x;
    if (i < GGR * HCC) pooled[i] = -INFINITY;
}

__global__ void pool_max(const ushort* __restrict__ xf, const int* __restrict__ batch,
                         float* __restrict__ pooled)
{
    int i = blockIdx.x * 256 + threadIdx.x;
    if (i >= NN * HCC) return;
    int n = i >> 7, c = i & 127;
    atomicMaxF(&pooled[batch[n] * 128 + c], bf2f(xf[i]));
}

__global__ __launch_bounds__(512) void mlp1(const float* __restrict__ pooled,
                                            const float* __restrict__ w,
                                            const float* __restrict__ bias,
                                            float* __restrict__ hid)
{
    __shared__ float xs[128];
    int g = blockIdx.x, t = threadIdx.x;
    if (t < 128) {
        float v = pooled[g * 128 + t];
        if (!isfinite(v)) v = 0.f;
        xs[t] = v;
    }
    __syncthreads();
    float acc = 0.f;
    #pragma unroll 8
    for (int k = 0; k < 128; ++k) acc += xs[k] * w[(size_t)k * NHIDD + t];
    hid[(size_t)g * NHIDD + t] = fmaxf(acc + bias[t], 0.f);
}

__global__ __launch_bounds__(768) void mlp2(const float* __restrict__ hid,
                                            const float* __restrict__ w,
                                            const float* __restrict__ bias,
                                            float* __restrict__ out)
{
    __shared__ float xs[NHIDD];
    int g = blockIdx.x, t = threadIdx.x;
    if (t < NHIDD) xs[t] = hid[(size_t)g * NHIDD + t];
    __syncthreads();
    float acc = 0.f;
    #pragma unroll 8
    for (int k = 0; k < NHIDD; ++k) acc += xs[k] * w[(size_t)k * NOUTD + t];
    out[(size_t)g * NOUTD + t] = acc + bias[t];
}

extern "C" void kernel_launch(void* const* d_in, const int* in_sizes, int n_in,
                              void* d_out, int out_size, void* d_ws, size_t ws_size,
                              hipStream_t stream)
{
    const float* x = (const float*)d_in[0];
    const int* ei = (const int*)d_in[1];
    const int* batch = (const int*)d_in[2];
    const float* W[3]   = {(const float*)d_in[3],  (const float*)d_in[9],  (const float*)d_in[15]};
    const float* AS[3]  = {(const float*)d_in[4],  (const float*)d_in[10], (const float*)d_in[16]};
    const float* AD[3]  = {(const float*)d_in[5],  (const float*)d_in[11], (const float*)d_in[17]};
    const float* B[3]   = {(const float*)d_in[6],  (const float*)d_in[12], (const float*)d_in[18]};
    const float* SKW[3] = {(const float*)d_in[7],  (const float*)d_in[13], (const float*)d_in[19]};
    const float* SKB[3] = {(const float*)d_in[8],  (const float*)d_in[14], (const float*)d_in[20]};
    const float* m1w = (const float*)d_in[21];
    const float* m1b = (const float*)d_in[22];
    const float* m2w = (const float*)d_in[23];
    const float* m2b = (const float*)d_in[24];
    float* out = (float*)d_out;

    float* p = (float*)d_ws;
    ushort* bufA = (ushort*)p; p += (size_t)NN * HCC / 2;
    ushort* bufB = (ushort*)p; p += (size_t)NN * HCC / 2;
    ushort* xb   = (ushort*)p; p += (size_t)NN * HCC / 2;
    ushort* hbuf = (ushort*)p; p += (size_t)NN * HCC / 2;
    ushort* wt3  = (ushort*)p; p += 3 * 256 * 128 / 2;
    float* agg  = p; p += (size_t)NN * HCC;
    float* esrc = p; p += NN * 4;
    float* edst = p; p += NN * 4;
    float* pooled = p; p += GGR * HCC;
    float* hidden = p; p += GGR * NHIDD;
    int* counts    = (int*)p; p += NN;
    int* excl      = (int*)p; p += NN;
    int* row_start = (int*)p; p += NN + 4;
    int* cursor    = (int*)p; p += NN;
    int* csr_src   = (int*)p; p += EPE;
    int* blocksums = (int*)p; p += 64;
    int* blockoffs = (int*)p; p += 64;

    conv_x<<<(NN * HCC / 4 + 255) / 256, 256, 0, stream>>>(x, xb);
    for (int l = 0; l < 3; ++l)
        conv_w<<<(256 * 128 + 255) / 256, 256, 0, stream>>>(W[l], SKW[l], wt3 + l * 256 * 128);

    hist_zero<<<(NN + 255) / 256, 256, 0, stream>>>(counts);
    hist<<<(EPE + 255) / 256, 256, 0, stream>>>(ei, counts);
    scan_partial<<<SCAN_NBLK, 256, 0, stream>>>(counts, excl, blocksums);
    scan_sums<<<1, 64, 0, stream>>>(blocksums, blockoffs, row_start);
    scan_add<<<(NN + 255) / 256, 256, 0, stream>>>(excl, blockoffs, row_start, cursor);
    scatter_csr<<<(EPE + 255) / 256, 256, 0, stream>>>(ei, cursor, csr_src);

    const ushort* cur = xb;
    ushort* outs[3] = {bufA, bufB, bufA};
    for (int l = 0; l < 3; ++l) {
        gemm_mfma<<<MBLK, 256, 0, stream>>>(cur, wt3 + l * 256 * 128, SKB[l], B[l], hbuf, agg);
        node_attn<<<NN / 2, 256, 0, stream>>>(hbuf, AS[l], AD[l], esrc, edst);
        gat_aggr<<<NN, 128, 0, stream>>>(row_start, csr_src, esrc, edst, hbuf, agg, outs[l]);
        cur = outs[l];
    }
    pool_init<<<(GGR * HCC) / 256, 256, 0, stream>>>(pooled);
    pool_max<<<(NN * HCC + 255) / 256, 256, 0, stream>>>(cur, batch, pooled);
    mlp1<<<GGR, NHIDD, 0, stream>>>(pooled, m1w, m1b, hidden);
    mlp2<<<GGR, NOUTD, 0, stream>>>(hidden, m2w, m2b, out);
}

// Round 8
// 528.040 us; speedup vs baseline: 4.5589x; 1.0328x over previous
//
#include <hip/hip_runtime.h>
#include <hip/hip_bf16.h>
#include <math.h>

#define NN 50000
#define EE 800000
#define EPE 850000   // EE + NN self loops
#define HCC 128
#define GGR 256
#define NHIDD 512
#define NOUTD 768
#define CHUNK 256
#define CPAD (CHUNK + 8)
#define SCAN_NBLK ((NN + 1023) / 1024)   // 49
#define MBLK ((NN + 63) / 64)            // 782
#define NPAD 50176                        // counts replica stride (64B aligned)
#define NREP 8

typedef __attribute__((ext_vector_type(8))) short bf16x8;
typedef __attribute__((ext_vector_type(4))) float f32x4;

__device__ __forceinline__ void atomicMaxF(float* addr, float v) {
    if (v >= 0.f) atomicMax(reinterpret_cast<int*>(addr), __float_as_int(v));
    else atomicMin(reinterpret_cast<unsigned int*>(addr), __float_as_uint(v));
}

__device__ __forceinline__ float lrelu(float x) { return x > 0.f ? x : 0.2f * x; }

__device__ __forceinline__ ushort f2bf(float f) {
    unsigned u = __float_as_uint(f);
    unsigned r = (u + 0x7fffu + ((u >> 16) & 1u)) >> 16;   // RNE
    return (ushort)r;
}
__device__ __forceinline__ float bf2f(ushort b) {
    return __uint_as_float(((unsigned)b) << 16);
}

// ---------------- converts ----------------
__global__ void conv_x(const float* __restrict__ X, ushort* __restrict__ Xb) {
    int i = blockIdx.x * 256 + threadIdx.x;
    if (i < NN * HCC / 4) {
        float4 v = reinterpret_cast<const float4*>(X)[i];
        ushort4 o;
        o.x = f2bf(v.x); o.y = f2bf(v.y); o.z = f2bf(v.z); o.w = f2bf(v.w);
        reinterpret_cast<ushort4*>(Xb)[i] = o;
    }
}

__global__ void conv_w(const float* __restrict__ W, const float* __restrict__ SKW,
                       ushort* __restrict__ Wt) {
    int i = blockIdx.x * 256 + threadIdx.x;
    if (i >= 256 * 128) return;
    int n = i >> 7, k = i & 127;
    float v = (n < 128) ? W[(size_t)k * 128 + n] : SKW[(size_t)k * 128 + (n - 128)];
    Wt[i] = f2bf(v);
}

// ---------------- CSR build (XCD-replicated counters) ----------------
__global__ void hist_zero8(int* __restrict__ cnt8) {
    int i = blockIdx.x * 256 + threadIdx.x;
    if (i < NREP * NPAD) cnt8[i] = 0;
}

// replica = blockIdx&7 tracks the round-robin block->XCD mapping, so each
// replica's lines live in one XCD's L2 (correct regardless of mapping).
__global__ void hist8(const int* __restrict__ ei, int* __restrict__ cnt8) {
    int e = blockIdx.x * 256 + threadIdx.x;
    if (e >= EPE) return;
    int rep = blockIdx.x & 7;
    int d = (e < EE) ? ei[EE + e] : e - EE;
    atomicAdd(&cnt8[rep * NPAD + d], 1);
}

__global__ __launch_bounds__(256) void scan_partial(const int* __restrict__ cnt8,
                                                    int* __restrict__ excl,
                                                    int* __restrict__ blocksums)
{
    __shared__ int s[256];
    const int b = blockIdx.x, t = threadIdx.x;
    const int idx = b * 1024 + t * 4;
    int a[4] = {0, 0, 0, 0};
    #pragma unroll
    for (int j = 0; j < 4; ++j) {
        if (idx + j < NN) {
            int tot = 0;
            #pragma unroll
            for (int r = 0; r < NREP; ++r) tot += cnt8[r * NPAD + idx + j];
            a[j] = tot;
        }
    }
    int sum4 = a[0] + a[1] + a[2] + a[3];
    s[t] = sum4;
    __syncthreads();
    #pragma unroll
    for (int off = 1; off < 256; off <<= 1) {
        int add = (t >= off) ? s[t - off] : 0;
        __syncthreads();
        s[t] += add;
        __syncthreads();
    }
    int e0 = s[t] - sum4;
    if (idx + 0 < NN) excl[idx + 0] = e0;
    if (idx + 1 < NN) excl[idx + 1] = e0 + a[0];
    if (idx + 2 < NN) excl[idx + 2] = e0 + a[0] + a[1];
    if (idx + 3 < NN) excl[idx + 3] = e0 + a[0] + a[1] + a[2];
    if (t == 255) blocksums[b] = s[255];
}

__global__ __launch_bounds__(64) void scan_sums(int* __restrict__ blocksums,
                                                int* __restrict__ blockoffs,
                                                int* __restrict__ row_start)
{
    __shared__ int s[64];
    int t = threadIdx.x;
    int v = (t < SCAN_NBLK) ? blocksums[t] : 0;
    s[t] = v;
    __syncthreads();
    #pragma unroll
    for (int off = 1; off < 64; off <<= 1) {
        int add = (t >= off) ? s[t - off] : 0;
        __syncthreads();
        s[t] += add;
        __syncthreads();
    }
    if (t < SCAN_NBLK) blockoffs[t] = s[t] - v;
    if (t == 63) row_start[NN] = s[63];
}

// row_start + per-replica cursor bases
__global__ void scan_add(const int* __restrict__ excl, const int* __restrict__ blockoffs,
                         const int* __restrict__ cnt8,
                         int* __restrict__ row_start, int* __restrict__ cur8)
{
    int i = blockIdx.x * 256 + threadIdx.x;
    if (i >= NN) return;
    int v = excl[i] + blockoffs[i >> 10];
    row_start[i] = v;
    int c = v;
    #pragma unroll
    for (int r = 0; r < NREP; ++r) {
        cur8[r * NPAD + i] = c;
        c += cnt8[r * NPAD + i];
    }
}

// must use IDENTICAL edge->block mapping as hist8
__global__ void scatter_csr8(const int* __restrict__ ei, int* __restrict__ cur8,
                             int* __restrict__ csr_src) {
    int e = blockIdx.x * 256 + threadIdx.x;
    if (e >= EPE) return;
    int rep = blockIdx.x & 7;
    int s, d;
    if (e < EE) { s = ei[e]; d = ei[EE + e]; } else { s = d = e - EE; }
    int pos = atomicAdd(&cur8[rep * NPAD + d], 1);
    csr_src[pos] = s;
}

// ---------------- MFMA node GEMM: [64 rows] x [256 cols], K=128 ----------------
__global__ __launch_bounds__(256) void gemm_mfma(
    const ushort* __restrict__ Xb,   // [NN][128] bf16
    const ushort* __restrict__ Wt,   // [256][128] bf16
    const float* __restrict__ skb, const float* __restrict__ bb,
    ushort* __restrict__ Hout, float* __restrict__ Agg)
{
    __shared__ ushort Xs[64 * 128];          // 16 KB, XOR-swizzled rows
    const int r0 = blockIdx.x * 64;
    const int tid = threadIdx.x;
    const int w = tid >> 6;
    const int l = tid & 63;
    const int lm = l & 15;
    const int lk = l >> 4;

    #pragma unroll
    for (int it = 0; it < 4; ++it) {
        int slot = it * 256 + tid;
        int row = slot >> 4;
        int bc = (slot & 15) << 4;
        int n = r0 + row;
        bf16x8 v = (bf16x8)(short)0;
        if (n < NN) v = *reinterpret_cast<const bf16x8*>(Xb + (size_t)n * 128 + (bc >> 1));
        *reinterpret_cast<bf16x8*>(reinterpret_cast<char*>(Xs) + row * 256 + (bc ^ ((row & 7) << 4))) = v;
    }
    __syncthreads();

    f32x4 acc[4][4];
    #pragma unroll
    for (int nb = 0; nb < 4; ++nb)
        #pragma unroll
        for (int rf = 0; rf < 4; ++rf)
            acc[nb][rf] = (f32x4){0.f, 0.f, 0.f, 0.f};

    #pragma unroll
    for (int ks = 0; ks < 4; ++ks) {
        bf16x8 a[4];
        #pragma unroll
        for (int rf = 0; rf < 4; ++rf) {
            int row = rf * 16 + lm;
            int bc = (ks * 32 + lk * 8) * 2;
            a[rf] = *reinterpret_cast<const bf16x8*>(
                reinterpret_cast<const char*>(Xs) + row * 256 + (bc ^ ((row & 7) << 4)));
        }
        #pragma unroll
        for (int nb = 0; nb < 4; ++nb) {
            int ncol = (w * 4 + nb) * 16 + lm;
            bf16x8 b = *reinterpret_cast<const bf16x8*>(Wt + (size_t)ncol * 128 + ks * 32 + lk * 8);
            #pragma unroll
            for (int rf = 0; rf < 4; ++rf)
                acc[nb][rf] = __builtin_amdgcn_mfma_f32_16x16x32_bf16(a[rf], b, acc[nb][rf], 0, 0, 0);
        }
    }

    #pragma unroll
    for (int nb = 0; nb < 4; ++nb) {
        int ncol = (w * 4 + nb) * 16 + lm;
        #pragma unroll
        for (int rf = 0; rf < 4; ++rf) {
            #pragma unroll
            for (int r = 0; r < 4; ++r) {
                int n = r0 + rf * 16 + lk * 4 + r;
                if (n >= NN) continue;
                float v = acc[nb][rf][r];
                if (ncol < 128) {
                    Hout[(size_t)n * 128 + ncol] = f2bf(v);
                } else {
                    int c = ncol - 128;
                    Agg[(size_t)n * 128 + c] = v + skb[c] + bb[c];
                }
            }
        }
    }
}

// per-node attention coefficients e_src/e_dst [N,4] (bf16 h input)
__global__ __launch_bounds__(256) void node_attn(
    const ushort* __restrict__ Hb, const float* __restrict__ as_, const float* __restrict__ ad_,
    float* __restrict__ esrc, float* __restrict__ edst)
{
    int tid = threadIdx.x;
    int node = blockIdx.x * 2 + (tid >> 7);
    int t = tid & 127;
    if (node >= NN) return;
    float hv = bf2f(Hb[(size_t)node * 128 + t]);
    float p1 = hv * as_[t];
    float p2 = hv * ad_[t];
    #pragma unroll
    for (int o = 16; o > 0; o >>= 1) {
        p1 += __shfl_down(p1, o, 32);
        p2 += __shfl_down(p2, o, 32);
    }
    if ((t & 31) == 0) {
        esrc[node * 4 + (t >> 5)] = p1;
        edst[node * 4 + (t >> 5)] = p2;
    }
}

// ---------------- fused per-dst softmax + aggregate + skip + relu ----------------
__global__ __launch_bounds__(128) void gat_aggr(
    const int* __restrict__ row_start, const int* __restrict__ csr_src,
    const float* __restrict__ esrc, const float* __restrict__ edst,
    const ushort* __restrict__ Hb, const float* __restrict__ skipagg,
    ushort* __restrict__ outbuf)
{
    __shared__ int   lsrc[CHUNK];
    __shared__ float lw[4][CPAD];
    __shared__ float shsc[4];
    __shared__ float accbuf[8][HCC];
    const int d = blockIdx.x;
    const int t = threadIdx.x;
    const int hd = t >> 5;
    const int l = t & 31;
    const int slot = t >> 4;
    const int cg = t & 15;
    const int c0 = cg * 8;
    const int ghd = cg >> 2;
    const int r0 = row_start[d], r1 = row_start[d + 1];
    const float4 edv = *reinterpret_cast<const float4*>(edst + (size_t)d * 4);
    float acc[8] = {0.f, 0.f, 0.f, 0.f, 0.f, 0.f, 0.f, 0.f};
    float m_h = -INFINITY, z_h = 0.f;

    for (int base = r0; base < r1; base += CHUNK) {
        const int nc = min(CHUNK, r1 - base);
        __syncthreads();
        for (int i = t; i < nc; i += 128) {
            int s = csr_src[base + i];
            lsrc[i] = s;
            float4 ev = *reinterpret_cast<const float4*>(esrc + (size_t)s * 4);
            lw[0][i] = lrelu(ev.x + edv.x);
            lw[1][i] = lrelu(ev.y + edv.y);
            lw[2][i] = lrelu(ev.z + edv.z);
            lw[3][i] = lrelu(ev.w + edv.w);
        }
        __syncthreads();
        float mx = m_h;
        for (int i = l; i < nc; i += 32) mx = fmaxf(mx, lw[hd][i]);
        #pragma unroll
        for (int off = 16; off > 0; off >>= 1) mx = fmaxf(mx, __shfl_xor(mx, off, 32));
        float sc = __expf(m_h - mx);
        float zp = 0.f;
        for (int i = l; i < nc; i += 32) {
            float w = __expf(lw[hd][i] - mx);
            lw[hd][i] = w;
            zp += w;
        }
        #pragma unroll
        for (int off = 16; off > 0; off >>= 1) zp += __shfl_xor(zp, off, 32);
        z_h = z_h * sc + zp;
        m_h = mx;
        if (l == 0) shsc[hd] = sc;
        __syncthreads();
        float scg = shsc[ghd];
        #pragma unroll
        for (int j = 0; j < 8; ++j) acc[j] *= scg;
        for (int i = slot; i < nc; i += 8) {
            int s = lsrc[i];
            float wgt = lw[ghd][i];
            bf16x8 row = *reinterpret_cast<const bf16x8*>(Hb + (size_t)s * 128 + c0);
            #pragma unroll
            for (int j = 0; j < 8; ++j)
                acc[j] = fmaf(wgt, bf2f((ushort)row[j]), acc[j]);
        }
    }
    #pragma unroll
    for (int j = 0; j < 8; ++j) accbuf[slot][c0 + j] = acc[j];
    __syncthreads();
    float tot = 0.f;
    #pragma unroll
    for (int s = 0; s < 8; ++s) tot += accbuf[s][t];
    float res = skipagg[(size_t)d * 128 + t] + tot / z_h;
    outbuf[(size_t)d * 128 + t] = f2bf(fmaxf(res, 0.f));
}

// ---------------- pooling + MLP ----------------
__global__ void pool_init(float* __restrict__ pooled) {
    int i = blockIdx.x * 256 + threadIdx.x;
    if (i < GGR * HCC) pooled[i] = -INFINITY;
}

// batch is sorted: run-reduce 32 nodes per block, ~1 atomic per (run,channel)
__global__ __launch_bounds__(256) void pool_max_sorted(
    const ushort* __restrict__ xf, const int* __restrict__ batch,
    float* __restrict__ pooled)
{
    __shared__ int gb[32];
    const int n0 = blockIdx.x * 32;
    const int t = threadIdx.x;
    if (t < 32) gb[t] = (n0 + t < NN) ? batch[n0 + t] : -1;
    __syncthreads();
    const int c = t & 127;
    const int half = t >> 7;              // 0/1 -> nodes [0,16) / [16,32)
    int curg = -1;
    float curv = -INFINITY;
    #pragma unroll 4
    for (int i = 0; i < 16; ++i) {
        int n = n0 + half * 16 + i;
        if (n >= NN) break;
        int g = gb[half * 16 + i];
        float v = bf2f(xf[(size_t)n * 128 + c]);
        if (g != curg) {
            if (curg >= 0) atomicMaxF(&pooled[curg * 128 + c], curv);
            curg = g; curv = v;
        } else {
            curv = fmaxf(curv, v);
        }
    }
    if (curg >= 0) atomicMaxF(&pooled[curg * 128 + c], curv);
}

__global__ __launch_bounds__(512) void mlp1(const float* __restrict__ pooled,
                                            const float* __restrict__ w,
                                            const float* __restrict__ bias,
                                            float* __restrict__ hid)
{
    __shared__ float xs[128];
    int g = blockIdx.x, t = threadIdx.x;
    if (t < 128) {
        float v = pooled[g * 128 + t];
        if (!isfinite(v)) v = 0.f;
        xs[t] = v;
    }
    __syncthreads();
    float acc = 0.f;
    #pragma unroll 8
    for (int k = 0; k < 128; ++k) acc += xs[k] * w[(size_t)k * NHIDD + t];
    hid[(size_t)g * NHIDD + t] = fmaxf(acc + bias[t], 0.f);
}

__global__ __launch_bounds__(768) void mlp2(const float* __restrict__ hid,
                                            const float* __restrict__ w,
                                            const float* __restrict__ bias,
                                            float* __restrict__ out)
{
    __shared__ float xs[NHIDD];
    int g = blockIdx.x, t = threadIdx.x;
    if (t < NHIDD) xs[t] = hid[(size_t)g * NHIDD + t];
    __syncthreads();
    float acc = 0.f;
    #pragma unroll 8
    for (int k = 0; k < NHIDD; ++k) acc += xs[k] * w[(size_t)k * NOUTD + t];
    out[(size_t)g * NOUTD + t] = acc + bias[t];
}

extern "C" void kernel_launch(void* const* d_in, const int* in_sizes, int n_in,
                              void* d_out, int out_size, void* d_ws, size_t ws_size,
                              hipStream_t stream)
{
    const float* x = (const float*)d_in[0];
    const int* ei = (const int*)d_in[1];
    const int* batch = (const int*)d_in[2];
    const float* W[3]   = {(const float*)d_in[3],  (const float*)d_in[9],  (const float*)d_in[15]};
    const float* AS[3]  = {(const float*)d_in[4],  (const float*)d_in[10], (const float*)d_in[16]};
    const float* AD[3]  = {(const float*)d_in[5],  (const float*)d_in[11], (const float*)d_in[17]};
    const float* B[3]   = {(const float*)d_in[6],  (const float*)d_in[12], (const float*)d_in[18]};
    const float* SKW[3] = {(const float*)d_in[7],  (const float*)d_in[13], (const float*)d_in[19]};
    const float* SKB[3] = {(const float*)d_in[8],  (const float*)d_in[14], (const float*)d_in[20]};
    const float* m1w = (const float*)d_in[21];
    const float* m1b = (const float*)d_in[22];
    const float* m2w = (const float*)d_in[23];
    const float* m2b = (const float*)d_in[24];
    float* out = (float*)d_out;

    float* p = (float*)d_ws;
    ushort* bufA = (ushort*)p; p += (size_t)NN * HCC / 2;
    ushort* bufB = (ushort*)p; p += (size_t)NN * HCC / 2;
    ushort* xb   = (ushort*)p; p += (size_t)NN * HCC / 2;
    ushort* hbuf = (ushort*)p; p += (size_t)NN * HCC / 2;
    ushort* wt3  = (ushort*)p; p += 3 * 256 * 128 / 2;
    float* agg  = p; p += (size_t)NN * HCC;
    float* esrc = p; p += NN * 4;
    float* edst = p; p += NN * 4;
    float* pooled = p; p += GGR * HCC;
    float* hidden = p; p += GGR * NHIDD;
    int* cnt8      = (int*)p; p += NREP * NPAD;
    int* cur8      = (int*)p; p += NREP * NPAD;
    int* excl      = (int*)p; p += NN;
    int* row_start = (int*)p; p += NN + 4;
    int* csr_src   = (int*)p; p += EPE;
    int* blocksums = (int*)p; p += 64;
    int* blockoffs = (int*)p; p += 64;

    conv_x<<<(NN * HCC / 4 + 255) / 256, 256, 0, stream>>>(x, xb);
    for (int l = 0; l < 3; ++l)
        conv_w<<<(256 * 128 + 255) / 256, 256, 0, stream>>>(W[l], SKW[l], wt3 + l * 256 * 128);

    hist_zero8<<<(NREP * NPAD + 255) / 256, 256, 0, stream>>>(cnt8);
    hist8<<<(EPE + 255) / 256, 256, 0, stream>>>(ei, cnt8);
    scan_partial<<<SCAN_NBLK, 256, 0, stream>>>(cnt8, excl, blocksums);
    scan_sums<<<1, 64, 0, stream>>>(blocksums, blockoffs, row_start);
    scan_add<<<(NN + 255) / 256, 256, 0, stream>>>(excl, blockoffs, cnt8, row_start, cur8);
    scatter_csr8<<<(EPE + 255) / 256, 256, 0, stream>>>(ei, cur8, csr_src);

    const ushort* cur = xb;
    ushort* outs[3] = {bufA, bufB, bufA};
    for (int l = 0; l < 3; ++l) {
        gemm_mfma<<<MBLK, 256, 0, stream>>>(cur, wt3 + l * 256 * 128, SKB[l], B[l], hbuf, agg);
        node_attn<<<NN / 2, 256, 0, stream>>>(hbuf, AS[l], AD[l], esrc, edst);
        gat_aggr<<<NN, 128, 0, stream>>>(row_start, csr_src, esrc, edst, hbuf, agg, outs[l]);
        cur = outs[l];
    }
    pool_init<<<(GGR * HCC) / 256, 256, 0, stream>>>(pooled);
    pool_max_sorted<<<(NN + 31) / 32, 256, 0, stream>>>(cur, batch, pooled);
    mlp1<<<GGR, NHIDD, 0, stream>>>(pooled, m1w, m1b, hidden);
    mlp2<<<GGR, NOUTD, 0, stream>>>(hidden, m2w, m2b, out);
}

// Round 9
// 494.078 us; speedup vs baseline: 4.8723x; 1.0687x over previous
//
#include <hip/hip_runtime.h>
#include <hip/hip_bf16.h>
#include <math.h>

#define NN 50000
#define EE 800000
#define EPE 850000   // EE + NN self loops
#define HCC 128
#define GGR 256
#define NHIDD 512
#define NOUTD 768
#define CHUNK 256
#define CPAD (CHUNK + 8)
#define SCAN_NBLK ((NN + 1023) / 1024)   // 49
#define MBLK ((NN + 63) / 64)            // 782
#define NPAD 50176                        // counts replica stride (64B aligned)
#define NREP 8
#define NPART (NN / 8)                    // 6250 dst per partition

typedef __attribute__((ext_vector_type(8))) short bf16x8;
typedef __attribute__((ext_vector_type(4))) float f32x4;

__device__ __forceinline__ void atomicMaxF(float* addr, float v) {
    if (v >= 0.f) atomicMax(reinterpret_cast<int*>(addr), __float_as_int(v));
    else atomicMin(reinterpret_cast<unsigned int*>(addr), __float_as_uint(v));
}

__device__ __forceinline__ float lrelu(float x) { return x > 0.f ? x : 0.2f * x; }

__device__ __forceinline__ ushort f2bf(float f) {
    unsigned u = __float_as_uint(f);
    unsigned r = (u + 0x7fffu + ((u >> 16) & 1u)) >> 16;   // RNE
    return (ushort)r;
}
__device__ __forceinline__ float bf2f(ushort b) {
    return __uint_as_float(((unsigned)b) << 16);
}

// ---------------- converts ----------------
__global__ void conv_x(const float* __restrict__ X, ushort* __restrict__ Xb) {
    int i = blockIdx.x * 256 + threadIdx.x;
    if (i < NN * HCC / 4) {
        float4 v = reinterpret_cast<const float4*>(X)[i];
        ushort4 o;
        o.x = f2bf(v.x); o.y = f2bf(v.y); o.z = f2bf(v.z); o.w = f2bf(v.w);
        reinterpret_cast<ushort4*>(Xb)[i] = o;
    }
}

__global__ void conv_w(const float* __restrict__ W, const float* __restrict__ SKW,
                       ushort* __restrict__ Wt) {
    int i = blockIdx.x * 256 + threadIdx.x;
    if (i >= 256 * 128) return;
    int n = i >> 7, k = i & 127;
    float v = (n < 128) ? W[(size_t)k * 128 + n] : SKW[(size_t)k * 128 + (n - 128)];
    Wt[i] = f2bf(v);
}

// ---------------- CSR build ----------------
__global__ void hist_zero8(int* __restrict__ cnt8) {
    int i = blockIdx.x * 256 + threadIdx.x;
    if (i < NREP * NPAD) cnt8[i] = 0;
}

__global__ void hist8(const int* __restrict__ ei, int* __restrict__ cnt8) {
    int e = blockIdx.x * 256 + threadIdx.x;
    if (e >= EPE) return;
    int rep = blockIdx.x & 7;
    int d = (e < EE) ? ei[EE + e] : e - EE;
    atomicAdd(&cnt8[rep * NPAD + d], 1);
}

__global__ __launch_bounds__(256) void scan_partial(const int* __restrict__ cnt8,
                                                    int* __restrict__ excl,
                                                    int* __restrict__ blocksums)
{
    __shared__ int s[256];
    const int b = blockIdx.x, t = threadIdx.x;
    const int idx = b * 1024 + t * 4;
    int a[4] = {0, 0, 0, 0};
    #pragma unroll
    for (int j = 0; j < 4; ++j) {
        if (idx + j < NN) {
            int tot = 0;
            #pragma unroll
            for (int r = 0; r < NREP; ++r) tot += cnt8[r * NPAD + idx + j];
            a[j] = tot;
        }
    }
    int sum4 = a[0] + a[1] + a[2] + a[3];
    s[t] = sum4;
    __syncthreads();
    #pragma unroll
    for (int off = 1; off < 256; off <<= 1) {
        int add = (t >= off) ? s[t - off] : 0;
        __syncthreads();
        s[t] += add;
        __syncthreads();
    }
    int e0 = s[t] - sum4;
    if (idx + 0 < NN) excl[idx + 0] = e0;
    if (idx + 1 < NN) excl[idx + 1] = e0 + a[0];
    if (idx + 2 < NN) excl[idx + 2] = e0 + a[0] + a[1];
    if (idx + 3 < NN) excl[idx + 3] = e0 + a[0] + a[1] + a[2];
    if (t == 255) blocksums[b] = s[255];
}

__global__ __launch_bounds__(64) void scan_sums(int* __restrict__ blocksums,
                                                int* __restrict__ blockoffs,
                                                int* __restrict__ row_start)
{
    __shared__ int s[64];
    int t = threadIdx.x;
    int v = (t < SCAN_NBLK) ? blocksums[t] : 0;
    s[t] = v;
    __syncthreads();
    #pragma unroll
    for (int off = 1; off < 64; off <<= 1) {
        int add = (t >= off) ? s[t - off] : 0;
        __syncthreads();
        s[t] += add;
        __syncthreads();
    }
    if (t < SCAN_NBLK) blockoffs[t] = s[t] - v;
    if (t == 63) row_start[NN] = s[63];
}

__global__ void scan_add(const int* __restrict__ excl, const int* __restrict__ blockoffs,
                         int* __restrict__ row_start, int* __restrict__ cursor)
{
    int i = blockIdx.x * 256 + threadIdx.x;
    if (i >= NN) return;
    int v = excl[i] + blockoffs[i >> 10];
    row_start[i] = v;
    cursor[i] = v;
}

// dst-range-partitioned scatter: partition p = blockIdx&7 (tracks XCD round-robin)
// handles only dst in [p*NPART,(p+1)*NPART) -> cursor atomics and csr_src lines
// are single-XCD; each partition re-scans the dst stream (coalesced).
__global__ __launch_bounds__(256) void scatter_part(const int* __restrict__ ei,
                                                    int* __restrict__ cursor,
                                                    int* __restrict__ csr_src)
{
    const int p = blockIdx.x & 7;
    const int q = blockIdx.x >> 3;
    const int nq = gridDim.x >> 3;
    const int lo = p * NPART, hi = lo + NPART;
    const int stride = nq * 256;
    for (int e = q * 256 + threadIdx.x; e < EE; e += stride) {
        int d = ei[EE + e];
        if (d >= lo && d < hi) {
            int s = ei[e];
            int pos = atomicAdd(&cursor[d], 1);
            csr_src[pos] = s;
        }
    }
    for (int i = q * 256 + threadIdx.x; i < NPART; i += stride) {
        int d = lo + i;
        int pos = atomicAdd(&cursor[d], 1);
        csr_src[pos] = d;
    }
}

// ---------------- MFMA node GEMM + fused attention coefficients ----------------
// [64 rows] x [256 cols], K=128; cols<128 -> h(bf16) + esrc/edst, cols>=128 -> skip(fp32)
__global__ __launch_bounds__(256) void gemm_mfma(
    const ushort* __restrict__ Xb,   // [NN][128] bf16
    const ushort* __restrict__ Wt,   // [256][128] bf16
    const float* __restrict__ skb, const float* __restrict__ bb,
    const float* __restrict__ as_, const float* __restrict__ ad_,
    ushort* __restrict__ Hout, float* __restrict__ Agg,
    float* __restrict__ esrc, float* __restrict__ edst)
{
    __shared__ ushort Xs[64 * 128];          // 16 KB, XOR-swizzled rows
    __shared__ float sh_es[64][4], sh_ed[64][4];
    const int r0 = blockIdx.x * 64;
    const int tid = threadIdx.x;
    const int w = tid >> 6;
    const int l = tid & 63;
    const int lm = l & 15;
    const int lk = l >> 4;

    #pragma unroll
    for (int it = 0; it < 4; ++it) {
        int slot = it * 256 + tid;
        int row = slot >> 4;
        int bc = (slot & 15) << 4;
        int n = r0 + row;
        bf16x8 v = (bf16x8)(short)0;
        if (n < NN) v = *reinterpret_cast<const bf16x8*>(Xb + (size_t)n * 128 + (bc >> 1));
        *reinterpret_cast<bf16x8*>(reinterpret_cast<char*>(Xs) + row * 256 + (bc ^ ((row & 7) << 4))) = v;
    }
    __syncthreads();

    f32x4 acc[4][4];
    #pragma unroll
    for (int nb = 0; nb < 4; ++nb)
        #pragma unroll
        for (int rf = 0; rf < 4; ++rf)
            acc[nb][rf] = (f32x4){0.f, 0.f, 0.f, 0.f};

    #pragma unroll
    for (int ks = 0; ks < 4; ++ks) {
        bf16x8 a[4];
        #pragma unroll
        for (int rf = 0; rf < 4; ++rf) {
            int row = rf * 16 + lm;
            int bc = (ks * 32 + lk * 8) * 2;
            a[rf] = *reinterpret_cast<const bf16x8*>(
                reinterpret_cast<const char*>(Xs) + row * 256 + (bc ^ ((row & 7) << 4)));
        }
        #pragma unroll
        for (int nb = 0; nb < 4; ++nb) {
            int ncol = (w * 4 + nb) * 16 + lm;
            bf16x8 b = *reinterpret_cast<const bf16x8*>(Wt + (size_t)ncol * 128 + ks * 32 + lk * 8);
            #pragma unroll
            for (int rf = 0; rf < 4; ++rf)
                acc[nb][rf] = __builtin_amdgcn_mfma_f32_16x16x32_bf16(a[rf], b, acc[nb][rf], 0, 0, 0);
        }
    }

    if (w < 2) {
        // h columns: write bf16 h and accumulate e_src/e_dst partials
        float asv[4], adv[4];
        #pragma unroll
        for (int nb = 0; nb < 4; ++nb) {
            int ncol = (w * 4 + nb) * 16 + lm;
            asv[nb] = as_[ncol];
            adv[nb] = ad_[ncol];
        }
        #pragma unroll
        for (int rf = 0; rf < 4; ++rf) {
            #pragma unroll
            for (int r = 0; r < 4; ++r) {
                int nl = rf * 16 + lk * 4 + r;
                int n = r0 + nl;
                float es0 = 0.f, es1 = 0.f, ed0 = 0.f, ed1 = 0.f;
                #pragma unroll
                for (int nb = 0; nb < 4; ++nb) {
                    float v = acc[nb][rf][r];
                    int ncol = (w * 4 + nb) * 16 + lm;
                    if (n < NN) Hout[(size_t)n * 128 + ncol] = f2bf(v);
                    if (nb < 2) { es0 = fmaf(v, asv[nb], es0); ed0 = fmaf(v, adv[nb], ed0); }
                    else        { es1 = fmaf(v, asv[nb], es1); ed1 = fmaf(v, adv[nb], ed1); }
                }
                // reduce across the 16 lm-lanes
                #pragma unroll
                for (int m = 1; m < 16; m <<= 1) {
                    es0 += __shfl_xor(es0, m); ed0 += __shfl_xor(ed0, m);
                    es1 += __shfl_xor(es1, m); ed1 += __shfl_xor(ed1, m);
                }
                if (lm == 0) {
                    sh_es[nl][w * 2 + 0] = es0; sh_ed[nl][w * 2 + 0] = ed0;
                    sh_es[nl][w * 2 + 1] = es1; sh_ed[nl][w * 2 + 1] = ed1;
                }
            }
        }
    } else {
        // skip columns
        #pragma unroll
        for (int nb = 0; nb < 4; ++nb) {
            int ncol = (w * 4 + nb) * 16 + lm;
            int c = ncol - 128;
            #pragma unroll
            for (int rf = 0; rf < 4; ++rf) {
                #pragma unroll
                for (int r = 0; r < 4; ++r) {
                    int n = r0 + rf * 16 + lk * 4 + r;
                    if (n >= NN) continue;
                    Agg[(size_t)n * 128 + c] = acc[nb][rf][r] + skb[c] + bb[c];
                }
            }
        }
    }
    __syncthreads();
    if (tid < 256) {
        int nl = tid >> 2, hd = tid & 3;
        int n = r0 + nl;
        if (n < NN) {
            esrc[n * 4 + hd] = sh_es[nl][hd];
            edst[n * 4 + hd] = sh_ed[nl][hd];
        }
    }
}

// ---------------- fused per-dst softmax + aggregate + skip + relu ----------------
__global__ __launch_bounds__(128) void gat_aggr(
    const int* __restrict__ row_start, const int* __restrict__ csr_src,
    const float* __restrict__ esrc, const float* __restrict__ edst,
    const ushort* __restrict__ Hb, const float* __restrict__ skipagg,
    ushort* __restrict__ outbuf)
{
    __shared__ int   lsrc[CHUNK];
    __shared__ float lw[4][CPAD];
    __shared__ float shsc[4];
    __shared__ float accbuf[8][HCC];
    const int d = blockIdx.x;
    const int t = threadIdx.x;
    const int hd = t >> 5;
    const int l = t & 31;
    const int slot = t >> 4;
    const int cg = t & 15;
    const int c0 = cg * 8;
    const int ghd = cg >> 2;
    const int r0 = row_start[d], r1 = row_start[d + 1];
    const float4 edv = *reinterpret_cast<const float4*>(edst + (size_t)d * 4);
    float acc[8] = {0.f, 0.f, 0.f, 0.f, 0.f, 0.f, 0.f, 0.f};
    float m_h = -INFINITY, z_h = 0.f;

    for (int base = r0; base < r1; base += CHUNK) {
        const int nc = min(CHUNK, r1 - base);
        __syncthreads();
        for (int i = t; i < nc; i += 128) {
            int s = csr_src[base + i];
            lsrc[i] = s;
            float4 ev = *reinterpret_cast<const float4*>(esrc + (size_t)s * 4);
            lw[0][i] = lrelu(ev.x + edv.x);
            lw[1][i] = lrelu(ev.y + edv.y);
            lw[2][i] = lrelu(ev.z + edv.z);
            lw[3][i] = lrelu(ev.w + edv.w);
        }
        __syncthreads();
        float mx = m_h;
        for (int i = l; i < nc; i += 32) mx = fmaxf(mx, lw[hd][i]);
        #pragma unroll
        for (int off = 16; off > 0; off >>= 1) mx = fmaxf(mx, __shfl_xor(mx, off, 32));
        float sc = __expf(m_h - mx);
        float zp = 0.f;
        for (int i = l; i < nc; i += 32) {
            float w = __expf(lw[hd][i] - mx);
            lw[hd][i] = w;
            zp += w;
        }
        #pragma unroll
        for (int off = 16; off > 0; off >>= 1) zp += __shfl_xor(zp, off, 32);
        z_h = z_h * sc + zp;
        m_h = mx;
        if (l == 0) shsc[hd] = sc;
        __syncthreads();
        float scg = shsc[ghd];
        #pragma unroll
        for (int j = 0; j < 8; ++j) acc[j] *= scg;
        for (int i = slot; i < nc; i += 8) {
            int s = lsrc[i];
            float wgt = lw[ghd][i];
            bf16x8 row = *reinterpret_cast<const bf16x8*>(Hb + (size_t)s * 128 + c0);
            #pragma unroll
            for (int j = 0; j < 8; ++j)
                acc[j] = fmaf(wgt, bf2f((ushort)row[j]), acc[j]);
        }
    }
    #pragma unroll
    for (int j = 0; j < 8; ++j) accbuf[slot][c0 + j] = acc[j];
    __syncthreads();
    float tot = 0.f;
    #pragma unroll
    for (int s = 0; s < 8; ++s) tot += accbuf[s][t];
    float res = skipagg[(size_t)d * 128 + t] + tot / z_h;
    outbuf[(size_t)d * 128 + t] = f2bf(fmaxf(res, 0.f));
}

// ---------------- pooling + MLP ----------------
__global__ void pool_init(float* __restrict__ pooled) {
    int i = blockIdx.x * 256 + threadIdx.x;
    if (i < GGR * HCC) pooled[i] = -INFINITY;
}

__global__ __launch_bounds__(256) void pool_max_sorted(
    const ushort* __restrict__ xf, const int* __restrict__ batch,
    float* __restrict__ pooled)
{
    __shared__ int gb[32];
    const int n0 = blockIdx.x * 32;
    const int t = threadIdx.x;
    if (t < 32) gb[t] = (n0 + t < NN) ? batch[n0 + t] : -1;
    __syncthreads();
    const int c = t & 127;
    const int half = t >> 7;
    int curg = -1;
    float curv = -INFINITY;
    #pragma unroll 4
    for (int i = 0; i < 16; ++i) {
        int n = n0 + half * 16 + i;
        if (n >= NN) break;
        int g = gb[half * 16 + i];
        float v = bf2f(xf[(size_t)n * 128 + c]);
        if (g != curg) {
            if (curg >= 0) atomicMaxF(&pooled[curg * 128 + c], curv);
            curg = g; curv = v;
        } else {
            curv = fmaxf(curv, v);
        }
    }
    if (curg >= 0) atomicMaxF(&pooled[curg * 128 + c], curv);
}

__global__ __launch_bounds__(512) void mlp1(const float* __restrict__ pooled,
                                            const float* __restrict__ w,
                                            const float* __restrict__ bias,
                                            float* __restrict__ hid)
{
    __shared__ float xs[128];
    int g = blockIdx.x, t = threadIdx.x;
    if (t < 128) {
        float v = pooled[g * 128 + t];
        if (!isfinite(v)) v = 0.f;
        xs[t] = v;
    }
    __syncthreads();
    float acc = 0.f;
    #pragma unroll 8
    for (int k = 0; k < 128; ++k) acc += xs[k] * w[(size_t)k * NHIDD + t];
    hid[(size_t)g * NHIDD + t] = fmaxf(acc + bias[t], 0.f);
}

__global__ __launch_bounds__(768) void mlp2(const float* __restrict__ hid,
                                            const float* __restrict__ w,
                                            const float* __restrict__ bias,
                                            float* __restrict__ out)
{
    __shared__ float xs[NHIDD];
    int g = blockIdx.x, t = threadIdx.x;
    if (t < NHIDD) xs[t] = hid[(size_t)g * NHIDD + t];
    __syncthreads();
    float acc = 0.f;
    #pragma unroll 8
    for (int k = 0; k < NHIDD; ++k) acc += xs[k] * w[(size_t)k * NOUTD + t];
    out[(size_t)g * NOUTD + t] = acc + bias[t];
}

extern "C" void kernel_launch(void* const* d_in, const int* in_sizes, int n_in,
                              void* d_out, int out_size, void* d_ws, size_t ws_size,
                              hipStream_t stream)
{
    const float* x = (const float*)d_in[0];
    const int* ei = (const int*)d_in[1];
    const int* batch = (const int*)d_in[2];
    const float* W[3]   = {(const float*)d_in[3],  (const float*)d_in[9],  (const float*)d_in[15]};
    const float* AS[3]  = {(const float*)d_in[4],  (const float*)d_in[10], (const float*)d_in[16]};
    const float* AD[3]  = {(const float*)d_in[5],  (const float*)d_in[11], (const float*)d_in[17]};
    const float* B[3]   = {(const float*)d_in[6],  (const float*)d_in[12], (const float*)d_in[18]};
    const float* SKW[3] = {(const float*)d_in[7],  (const float*)d_in[13], (const float*)d_in[19]};
    const float* SKB[3] = {(const float*)d_in[8],  (const float*)d_in[14], (const float*)d_in[20]};
    const float* m1w = (const float*)d_in[21];
    const float* m1b = (const float*)d_in[22];
    const float* m2w = (const float*)d_in[23];
    const float* m2b = (const float*)d_in[24];
    float* out = (float*)d_out;

    float* p = (float*)d_ws;
    ushort* bufA = (ushort*)p; p += (size_t)NN * HCC / 2;
    ushort* bufB = (ushort*)p; p += (size_t)NN * HCC / 2;
    ushort* xb   = (ushort*)p; p += (size_t)NN * HCC / 2;
    ushort* hbuf = (ushort*)p; p += (size_t)NN * HCC / 2;
    ushort* wt3  = (ushort*)p; p += 3 * 256 * 128 / 2;
    float* agg  = p; p += (size_t)NN * HCC;
    float* esrc = p; p += NN * 4;
    float* edst = p; p += NN * 4;
    float* pooled = p; p += GGR * HCC;
    float* hidden = p; p += GGR * NHIDD;
    int* cnt8      = (int*)p; p += NREP * NPAD;
    int* cursor    = (int*)p; p += NN;
    int* excl      = (int*)p; p += NN;
    int* row_start = (int*)p; p += NN + 4;
    int* csr_src   = (int*)p; p += EPE;
    int* blocksums = (int*)p; p += 64;
    int* blockoffs = (int*)p; p += 64;

    conv_x<<<(NN * HCC / 4 + 255) / 256, 256, 0, stream>>>(x, xb);
    for (int l = 0; l < 3; ++l)
        conv_w<<<(256 * 128 + 255) / 256, 256, 0, stream>>>(W[l], SKW[l], wt3 + l * 256 * 128);

    hist_zero8<<<(NREP * NPAD + 255) / 256, 256, 0, stream>>>(cnt8);
    hist8<<<(EPE + 255) / 256, 256, 0, stream>>>(ei, cnt8);
    scan_partial<<<SCAN_NBLK, 256, 0, stream>>>(cnt8, excl, blocksums);
    scan_sums<<<1, 64, 0, stream>>>(blocksums, blockoffs, row_start);
    scan_add<<<(NN + 255) / 256, 256, 0, stream>>>(excl, blockoffs, row_start, cursor);
    scatter_part<<<1024, 256, 0, stream>>>(ei, cursor, csr_src);

    const ushort* cur = xb;
    ushort* outs[3] = {bufA, bufB, bufA};
    for (int l = 0; l < 3; ++l) {
        gemm_mfma<<<MBLK, 256, 0, stream>>>(cur, wt3 + l * 256 * 128, SKB[l], B[l],
                                            AS[l], AD[l], hbuf, agg, esrc, edst);
        gat_aggr<<<NN, 128, 0, stream>>>(row_start, csr_src, esrc, edst, hbuf, agg, outs[l]);
        cur = outs[l];
    }
    pool_init<<<(GGR * HCC) / 256, 256, 0, stream>>>(pooled);
    pool_max_sorted<<<(NN + 31) / 32, 256, 0, stream>>>(cur, batch, pooled);
    mlp1<<<GGR, NHIDD, 0, stream>>>(pooled, m1w, m1b, hidden);
    mlp2<<<GGR, NOUTD, 0, stream>>>(hidden, m2w, m2b, out);
}